// Round 10
// baseline (142.298 us; speedup 1.0000x reference)
//
#include <hip/hip_runtime.h>
#include <stdint.h>

#define Bb 2
#define Ll 2048
#define Dd 1024
#define Hh 16
#define DKd 64
#define Mm (Bb*Ll)   // 4096

typedef __bf16 bf16_t;
typedef __bf16 bf16x8 __attribute__((ext_vector_type(8)));
typedef float f32x4 __attribute__((ext_vector_type(4)));
typedef unsigned u32x2 __attribute__((ext_vector_type(2)));

#define AS1C(p) ((const __attribute__((address_space(1))) void*)(p))
#define AS3(p)  ((__attribute__((address_space(3))) void*)(p))

__device__ __forceinline__ unsigned short bfu(float f){
  return __builtin_bit_cast(unsigned short, (bf16_t)f);   // native v_cvt, RTNE
}
__device__ __forceinline__ void wait_vm6(){  asm volatile("s_waitcnt vmcnt(6)"  ::: "memory"); }
__device__ __forceinline__ void wait_vm8(){  asm volatile("s_waitcnt vmcnt(8)"  ::: "memory"); }
__device__ __forceinline__ void wait_vm10(){ asm volatile("s_waitcnt vmcnt(10)" ::: "memory"); }
__device__ __forceinline__ void wait_vm0(){  asm volatile("s_waitcnt vmcnt(0)"  ::: "memory"); }
__device__ __forceinline__ void bar(){
  __builtin_amdgcn_sched_barrier(0);
  __builtin_amdgcn_s_barrier();
  __builtin_amdgcn_sched_barrier(0);
}

// ---------------- fp32 -> bf16 convert: all 7 buffers, one launch ----------------
struct Cvt7 { const float* in[7]; ushort4* out[7]; int n4[7]; };

__global__ void cvt_multi(Cvt7 a){
  const int z = blockIdx.y;
  int i = blockIdx.x*256 + threadIdx.x;
  if (i < a.n4[z]){
    float4 v = ((const float4*)a.in[z])[i];
    ushort4 o; o.x=bfu(v.x); o.y=bfu(v.y); o.z=bfu(v.z); o.w=bfu(v.w);
    a.out[z][i] = o;
  }
}

// ---------------- GEMM: C = A(MxK) * B(NxK)^T + bias ----------------
// mode 0: bf16 out, (B,H,L,DK); mode 1: fp32 row-major; mode 2: bf16 V^T (B,H,DK,L)
#define BM 128
#define BN 64
#define BKs 64

struct GemmArgs {
  const bf16_t* A[3];
  const bf16_t* W[3];
  const float*  bias[3];
  void*         out[3];
  float         scale[3];
  int           mode[3];
};

__device__ __forceinline__ void stage_tile(
    const bf16_t* __restrict__ A, const bf16_t* __restrict__ Bw,
    int m0, int n0, int K, int k0, bf16_t* As, bf16_t* Bs,
    int w, int srow, int scol)
{
#pragma unroll
  for (int i = 0; i < 4; i++) {
    int c = i*4 + w;
    int row = c*8 + srow;
    int sc = scol ^ ((row & 7) << 3);   // inverse-swizzled global source
    __builtin_amdgcn_global_load_lds(AS1C(A + (size_t)(m0+row)*K + k0 + sc),
                                     AS3(As + c*512), 16, 0, 0);
  }
#pragma unroll
  for (int i = 0; i < 2; i++) {
    int c = i*4 + w;
    int row = c*8 + srow;
    int sc = scol ^ ((row & 7) << 3);
    __builtin_amdgcn_global_load_lds(AS1C(Bw + (size_t)(n0+row)*K + k0 + sc),
                                     AS3(Bs + c*512), 16, 0, 0);
  }
}

__global__ __launch_bounds__(256) void gemm_bt(GemmArgs ga, int M, int N, int K)
{
  const int z = blockIdx.z;
  const bf16_t* __restrict__ A  = ga.A[z];
  const bf16_t* __restrict__ Bw = ga.W[z];
  const float*  __restrict__ bias = ga.bias[z];
  void* __restrict__ out = ga.out[z];
  const float scale = ga.scale[z];
  const int mode = ga.mode[z];

  __shared__ bf16_t As[2][BM*BKs];   // 2x16KB
  __shared__ bf16_t Bs[2][BN*BKs];   // 2x8KB
  const int tid = threadIdx.x;
  const int lane = tid & 63;
  const int w = tid >> 6;
  const int m0 = blockIdx.x * BM;
  const int n0 = blockIdx.y * BN;
  const int wr = (w >> 1) * 64, wc = (w & 1) * 32;
  const int lrow16 = lane & 15;
  const int kgrp = lane >> 4;
  const int srow = lane >> 3;
  const int scol = (lane & 7) * 8;

  f32x4 acc[4][2] = {};

  stage_tile(A, Bw, m0, n0, K, 0, As[0], Bs[0], w, srow, scol);

  const int KT = K / BKs;
  int cur = 0;
  for (int kt = 0; kt < KT; ++kt) {
    if (kt + 1 < KT) {
      stage_tile(A, Bw, m0, n0, K, (kt+1)*BKs, As[cur^1], Bs[cur^1], w, srow, scol);
      wait_vm6();              // tile kt done; kt+1 stays in flight
    } else {
      wait_vm0();
    }
    bar();                     // staging of [cur] visible to all waves
#pragma unroll
    for (int ks = 0; ks < 2; ++ks) {
      const int kbyte = ks*64 + kgrp*16;
      bf16x8 af[4], bfr[2];
#pragma unroll
      for (int m = 0; m < 4; m++) {
        int row = wr + m*16 + lrow16;
        af[m] = *(const bf16x8*)((const char*)As[cur] + row*128 + (kbyte ^ ((row & 7) << 4)));
      }
#pragma unroll
      for (int n = 0; n < 2; n++) {
        int row = wc + n*16 + lrow16;
        bfr[n] = *(const bf16x8*)((const char*)Bs[cur] + row*128 + (kbyte ^ ((row & 7) << 4)));
      }
#pragma unroll
      for (int m = 0; m < 4; m++)
#pragma unroll
        for (int n = 0; n < 2; n++)
          acc[m][n] = __builtin_amdgcn_mfma_f32_16x16x32_bf16(af[m], bfr[n], acc[m][n], 0, 0, 0);
    }
    bar();                     // all reads of [cur] complete before reuse
    cur ^= 1;
  }

#pragma unroll
  for (int m = 0; m < 4; m++)
#pragma unroll
    for (int n = 0; n < 2; n++) {
      const int row0 = m0 + wr + m*16 + kgrp*4;
      const int col  = n0 + wc + n*16 + lrow16;
      const float bcol = bias[col];
      if (mode == 2) {
        // V^T: (B,H,DK,L) — 4 consecutive l values pack to one 8B store
        int b = row0 >> 11, l0 = row0 & 2047;
        int h = col >> 6, dk = col & 63;
        ushort4 u;
        u.x = bfu((acc[m][n][0] + bcol) * scale);
        u.y = bfu((acc[m][n][1] + bcol) * scale);
        u.z = bfu((acc[m][n][2] + bcol) * scale);
        u.w = bfu((acc[m][n][3] + bcol) * scale);
        *(ushort4*)((unsigned short*)out + ((size_t)((b<<4) + h)*DKd + dk)*Ll + l0) = u;
      } else {
#pragma unroll
        for (int i = 0; i < 4; i++) {
          int row = row0 + i;
          float v = (acc[m][n][i] + bcol) * scale;
          if (mode == 1) {
            ((float*)out)[(size_t)row*N + col] = v;
          } else {
            int b = row >> 11, l = row & 2047;
            int h = col >> 6, dk = col & 63;
            ((unsigned short*)out)[((size_t)((b<<4) + h)*Ll + l)*DKd + dk] = bfu(v);
          }
        }
      }
    }
}

// ---------------- causal flash attention ----------------
// Round-6 geometry (512 blocks x 4 waves x 16 q-rows, uniform 33-step pairs
// (j, 31-j)), but V is read DIRECT from L2 (no LDS staging): PV B-fragments
// are bf16x8 global loads issued at step top, consumed after softmax.
// LDS = K (dbuf, swizzled) + per-wave P only (24KB).
#define KVB 64

__global__ __launch_bounds__(256) void attn_kernel(
    const bf16_t* __restrict__ Qh, const bf16_t* __restrict__ Kh,
    const bf16_t* __restrict__ VTg, unsigned short* __restrict__ Oa)
{
  const int id = blockIdx.x;                 // 0..511
  const int xcd = id & 7;                    // XCD pin
  const int hq  = (id >> 3) & 3;
  const int j   = id >> 5;                   // 0..15
  const int bh  = xcd + 8*hq;
  const int sA  = j;                         // last step of phase A (tile j)
  const int qtB = 31 - j;

  const int tid = threadIdx.x, lane = tid & 63, w = tid >> 6;   // w 0..3
  const int r = lane & 15, g = lane >> 4;

  const bf16_t* Qp  = Qh  + (size_t)bh * Ll * DKd;
  const bf16_t* Kp  = Kh  + (size_t)bh * Ll * DKd;
  const bf16_t* VTp = VTg + (size_t)bh * Ll * DKd;   // [dk][l]

  __shared__ bf16_t Klds[2][64*64];   // 16KB, XOR-swizzled 128B rows
  __shared__ bf16_t Plds[4][16*64];   // 8KB, per-wave P rows (q), swizzled

  int q0 = j * 64;
  // Q fragments for both phases, hoisted
  bf16x8 qf[2], qB[2];
#pragma unroll
  for (int ks = 0; ks < 2; ++ks) {
    qf[ks] = *(const bf16x8*)(Qp + (size_t)(q0 + w*16 + r)*DKd + ks*32 + g*8);
    qB[ks] = *(const bf16x8*)(Qp + (size_t)(qtB*64 + w*16 + r)*DKd + ks*32 + g*8);
  }

  bf16x8 ones;
#pragma unroll
  for (int jj = 0; jj < 8; ++jj) ones[jj] = (bf16_t)1.0f;

  f32x4 accO[4] = {};
  f32x4 accL = {};
  float mrow = -1e30f;

  const int krow_l = lane >> 3;                        // 0..7
  const int kcol_l = ((lane & 7)*16) ^ (krow_l << 4);  // swizzled source byte
  char* Pw = (char*)&Plds[w][0];
  const int rsw = (r & 7) << 4;
  const int b_ = bh >> 4, h_ = bh & 15;

  auto pre_K = [&](int kv, int buf){
#pragma unroll
    for (int i = 0; i < 2; ++i) {
      int c = i*4 + w;
      __builtin_amdgcn_global_load_lds(
        AS1C((const char*)Kp + (size_t)(kv*KVB + c*8 + krow_l)*128 + kcol_l),
        AS3((char*)&Klds[buf][0] + c*1024), 16, 0, 0);
    }
  };

  pre_K(0, 0);   // phase A, kv=0

  int cur = 0;
  for (int s = 0; s < 33; ++s) {
    const int kv0 = ((s <= sA) ? s : s - sA - 1) * KVB;

    // V^T fragments for THIS tile, direct from global (L2): 8 loads,
    // independent of everything -> in flight across QK + softmax.
    bf16x8 vfg[2][4];
#pragma unroll
    for (int ks = 0; ks < 2; ++ks)
#pragma unroll
      for (int n = 0; n < 4; ++n)
        vfg[ks][n] = *(const bf16x8*)(VTp + (size_t)(n*16 + r)*Ll + kv0 + ks*32 + g*8);

    if (s < 32) {
      int kv2 = (s < sA) ? s + 1 : s - sA;   // next step's kv
      pre_K(kv2, cur^1);                     // 2 gload_lds
      wait_vm10();   // outstanding: 8 vf + 2 preK -> K(s) (older) complete
    } else {
      wait_vm8();    // outstanding: 8 vf -> K(32) complete
    }
    bar();                       // Klds[cur] visible to all waves

    // S^T = K Q^T : sv[n][i] = S[q=q0+w*16+r][kv = kv0 + n*16 + g*4 + i]
    const char* Kbase = (const char*)&Klds[cur][0];
    f32x4 sv[4] = {};
    __builtin_amdgcn_s_setprio(1);
#pragma unroll
    for (int ks = 0; ks < 2; ++ks) {
      const int kbyte = ks*64 + g*16;
#pragma unroll
      for (int n = 0; n < 4; ++n) {
        int row = n*16 + r;
        bf16x8 kf = *(const bf16x8*)(Kbase + row*128 + (kbyte ^ ((row & 7) << 4)));
        sv[n] = __builtin_amdgcn_mfma_f32_16x16x32_bf16(kf, qf[ks], sv[n], 0, 0, 0);
      }
    }
    __builtin_amdgcn_s_setprio(0);

    // causal mask: diagonal tiles only (end of each phase)
    if (s == sA || s == 32) {
      const int qg = q0 + w*16 + r;
#pragma unroll
      for (int n = 0; n < 4; ++n)
#pragma unroll
        for (int i = 0; i < 4; ++i)
          if (kv0 + n*16 + g*4 + i > qg) sv[n][i] = -1e30f;
    }

    // in-register online softmax (log2 domain, defer-max)
    float m0 = fmaxf(fmaxf(sv[0][0], sv[0][1]), sv[0][2]);
    float m1 = fmaxf(fmaxf(sv[0][3], sv[1][0]), sv[1][1]);
    float m2 = fmaxf(fmaxf(sv[1][2], sv[1][3]), sv[2][0]);
    float m3 = fmaxf(fmaxf(sv[2][1], sv[2][2]), sv[2][3]);
    float m4 = fmaxf(fmaxf(sv[3][0], sv[3][1]), sv[3][2]);
    float mx = fmaxf(fmaxf(fmaxf(m0, m1), m2), fmaxf(fmaxf(m3, m4), sv[3][3]));
    if (__any(mx > mrow + 8.f)) {
      mx = fmaxf(mx, __shfl_xor(mx, 16));
      mx = fmaxf(mx, __shfl_xor(mx, 32));
      float mnew = fmaxf(mrow, mx);
      float corr = __builtin_amdgcn_exp2f(mrow - mnew);
      float c0 = __shfl(corr, g*4 + 0);
      float c1 = __shfl(corr, g*4 + 1);
      float c2 = __shfl(corr, g*4 + 2);
      float c3 = __shfl(corr, g*4 + 3);
#pragma unroll
      for (int n = 0; n < 4; ++n) {
        accO[n][0] *= c0; accO[n][1] *= c1; accO[n][2] *= c2; accO[n][3] *= c3;
      }
      accL[0] *= c0; accL[1] *= c1; accL[2] *= c2; accL[3] *= c3;
      mrow = mnew;
    }
#pragma unroll
    for (int n = 0; n < 4; ++n)
#pragma unroll
      for (int i = 0; i < 4; ++i)
        sv[n][i] = __builtin_amdgcn_exp2f(sv[n][i] - mrow);

    // pack P -> per-wave LDS: 4 x b64 swizzled writes (same-wave, no barrier)
#pragma unroll
    for (int n = 0; n < 4; ++n) {
      unsigned lo = (unsigned)bfu(sv[n][0]) | ((unsigned)bfu(sv[n][1]) << 16);
      unsigned hi = (unsigned)bfu(sv[n][2]) | ((unsigned)bfu(sv[n][3]) << 16);
      u32x2 pk; pk[0] = lo; pk[1] = hi;
      *(u32x2*)(Pw + r*128 + ((n*32 + g*8) ^ rsw)) = pk;
    }

    // PV: O += P * V, l += P * 1 (V fragments already in regs via L2)
    __builtin_amdgcn_s_setprio(1);
#pragma unroll
    for (int ks = 0; ks < 2; ++ks) {
      const int kbyte = ks*64 + g*16;
      bf16x8 pa = *(const bf16x8*)(Pw + r*128 + (kbyte ^ rsw));
      accL = __builtin_amdgcn_mfma_f32_16x16x32_bf16(pa, ones, accL, 0, 0, 0);
#pragma unroll
      for (int n = 0; n < 4; ++n)
        accO[n] = __builtin_amdgcn_mfma_f32_16x16x32_bf16(pa, vfg[ks][n], accO[n], 0, 0, 0);
    }
    __builtin_amdgcn_s_setprio(0);

    // phase A finished: store, reset, switch to tile B's Q
    if (s == sA) {
#pragma unroll
      for (int i = 0; i < 4; ++i) {
        float inv = 1.f / accL[i];
        int q = q0 + w*16 + g*4 + i;
#pragma unroll
        for (int n = 0; n < 4; ++n)
          Oa[((size_t)(b_*Ll + q))*Dd + h_*DKd + n*16 + r] = bfu(accO[n][i] * inv);
      }
      q0 = qtB * 64;
      qf[0] = qB[0]; qf[1] = qB[1];
#pragma unroll
      for (int n = 0; n < 4; ++n) accO[n] = f32x4{};
      accL = f32x4{};
      mrow = -1e30f;
    }

    bar();                       // all reads of Klds[cur] done before reuse
    cur ^= 1;
  }

  // phase B store
#pragma unroll
  for (int i = 0; i < 4; ++i) {
    float inv = 1.f / accL[i];
    int q = q0 + w*16 + g*4 + i;
#pragma unroll
    for (int n = 0; n < 4; ++n)
      Oa[((size_t)(b_*Ll + q))*Dd + h_*DKd + n*16 + r] = bfu(accO[n][i] * inv);
  }
}

// ---------------- launch ----------------
extern "C" void kernel_launch(void* const* d_in, const int* in_sizes, int n_in,
                              void* d_out, int out_size, void* d_ws, size_t ws_size,
                              hipStream_t stream)
{
  const float* q  = (const float*)d_in[0];
  const float* k  = (const float*)d_in[1];
  const float* v  = (const float*)d_in[2];
  // d_in[3] = mask (causal, hardcoded)
  const float* wq = (const float*)d_in[4];
  const float* bq = (const float*)d_in[5];
  const float* wk = (const float*)d_in[6];
  const float* bk = (const float*)d_in[7];
  const float* wv = (const float*)d_in[8];
  const float* bv = (const float*)d_in[9];
  const float* wo = (const float*)d_in[10];
  const float* bo = (const float*)d_in[11];

  char* ws = (char*)d_ws;
  bf16_t* Xq = (bf16_t*)(ws + 0);
  bf16_t* Xk = (bf16_t*)(ws + 8388608);
  bf16_t* Xv = (bf16_t*)(ws + 16777216);
  bf16_t* Wq = (bf16_t*)(ws + 25165824);
  bf16_t* Wk = (bf16_t*)(ws + 27262976);
  bf16_t* Wv = (bf16_t*)(ws + 29360128);
  bf16_t* Wo = (bf16_t*)(ws + 31457280);
  bf16_t* Qh = (bf16_t*)(ws + 33554432);
  bf16_t* Kh = (bf16_t*)(ws + 41943040);
  bf16_t* VT = (bf16_t*)(ws + 50331648);   // V^T (B,H,DK,L), written by V-GEMM
  bf16_t* Oa = (bf16_t*)(ws + 58720256);   // total 64 MiB

  const int NX4 = Mm * Dd / 4;   // 1048576
  const int NW4 = Dd * Dd / 4;   // 262144

  Cvt7 cv;
  cv.in[0]=q;  cv.out[0]=(ushort4*)Xq; cv.n4[0]=NX4;
  cv.in[1]=k;  cv.out[1]=(ushort4*)Xk; cv.n4[1]=NX4;
  cv.in[2]=v;  cv.out[2]=(ushort4*)Xv; cv.n4[2]=NX4;
  cv.in[3]=wq; cv.out[3]=(ushort4*)Wq; cv.n4[3]=NW4;
  cv.in[4]=wk; cv.out[4]=(ushort4*)Wk; cv.n4[4]=NW4;
  cv.in[5]=wv; cv.out[5]=(ushort4*)Wv; cv.n4[5]=NW4;
  cv.in[6]=wo; cv.out[6]=(ushort4*)Wo; cv.n4[6]=NW4;
  cvt_multi<<<dim3(NX4/256, 7), 256, 0, stream>>>(cv);

  const float qscale = 0.125f * 1.4426950408889634f;  // 1/sqrt(DK) * log2(e)
  GemmArgs gqkv;
  gqkv.A[0]=Xq; gqkv.A[1]=Xk; gqkv.A[2]=Xv;
  gqkv.W[0]=Wq; gqkv.W[1]=Wk; gqkv.W[2]=Wv;
  gqkv.bias[0]=bq; gqkv.bias[1]=bk; gqkv.bias[2]=bv;
  gqkv.out[0]=Qh; gqkv.out[1]=Kh; gqkv.out[2]=VT;
  gqkv.scale[0]=qscale; gqkv.scale[1]=1.0f; gqkv.scale[2]=1.0f;
  gqkv.mode[0]=0; gqkv.mode[1]=0; gqkv.mode[2]=2;     // V writes V^T directly
  gemm_bt<<<dim3(Mm/BM, Dd/BN, 3), 256, 0, stream>>>(gqkv, Mm, Dd, Dd);

  attn_kernel<<<dim3(512), 256, 0, stream>>>(Qh, Kh, VT, (unsigned short*)Oa);

  GemmArgs go;
  go.A[0]=Oa; go.A[1]=Oa; go.A[2]=Oa;
  go.W[0]=Wo; go.W[1]=Wo; go.W[2]=Wo;
  go.bias[0]=bo; go.bias[1]=bo; go.bias[2]=bo;
  go.out[0]=d_out; go.out[1]=d_out; go.out[2]=d_out;
  go.scale[0]=1.0f; go.scale[1]=1.0f; go.scale[2]=1.0f;
  go.mode[0]=1; go.mode[1]=1; go.mode[2]=1;
  gemm_bt<<<dim3(Mm/BM, Dd/BN, 1), 256, 0, stream>>>(go, Mm, Dd, Dd);
}

// Round 11
// 117.271 us; speedup vs baseline: 1.2134x; 1.2134x over previous
//
#include <hip/hip_runtime.h>
#include <stdint.h>

#define Bb 2
#define Ll 2048
#define Dd 1024
#define Hh 16
#define DKd 64
#define Mm (Bb*Ll)   // 4096

typedef __bf16 bf16_t;
typedef __bf16 bf16x8 __attribute__((ext_vector_type(8)));
typedef float f32x4 __attribute__((ext_vector_type(4)));
typedef unsigned u32x2 __attribute__((ext_vector_type(2)));

#define AS1C(p) ((const __attribute__((address_space(1))) void*)(p))
#define AS3(p)  ((__attribute__((address_space(3))) void*)(p))

__device__ __forceinline__ unsigned short bfu(float f){
  return __builtin_bit_cast(unsigned short, (bf16_t)f);   // native v_cvt, RTNE
}
__device__ __forceinline__ void wait_vm4(){ asm volatile("s_waitcnt vmcnt(4)" ::: "memory"); }
__device__ __forceinline__ void wait_vm6(){ asm volatile("s_waitcnt vmcnt(6)" ::: "memory"); }
__device__ __forceinline__ void wait_vm0(){ asm volatile("s_waitcnt vmcnt(0)" ::: "memory"); }
__device__ __forceinline__ void bar(){
  __builtin_amdgcn_sched_barrier(0);
  __builtin_amdgcn_s_barrier();
  __builtin_amdgcn_sched_barrier(0);
}

// ---------------- fp32 -> bf16 convert: all 7 buffers, one launch ----------------
struct Cvt7 { const float* in[7]; ushort4* out[7]; int n4[7]; };

__global__ void cvt_multi(Cvt7 a){
  const int z = blockIdx.y;
  int i = blockIdx.x*256 + threadIdx.x;
  if (i < a.n4[z]){
    float4 v = ((const float4*)a.in[z])[i];
    ushort4 o; o.x=bfu(v.x); o.y=bfu(v.y); o.z=bfu(v.z); o.w=bfu(v.w);
    a.out[z][i] = o;
  }
}

// ---------------- GEMM: C = A(MxK) * B(NxK)^T + bias ----------------
// mode 0: bf16 out, (B,H,L,DK); mode 1: fp32 row-major; mode 2: bf16 V^T (B,H,DK,L)
#define BM 128
#define BN 64
#define BKs 64

struct GemmArgs {
  const bf16_t* A[3];
  const bf16_t* W[3];
  const float*  bias[3];
  void*         out[3];
  float         scale[3];
  int           mode[3];
};

__device__ __forceinline__ void stage_tile(
    const bf16_t* __restrict__ A, const bf16_t* __restrict__ Bw,
    int m0, int n0, int K, int k0, bf16_t* As, bf16_t* Bs,
    int w, int srow, int scol)
{
#pragma unroll
  for (int i = 0; i < 4; i++) {
    int c = i*4 + w;
    int row = c*8 + srow;
    int sc = scol ^ ((row & 7) << 3);   // inverse-swizzled global source
    __builtin_amdgcn_global_load_lds(AS1C(A + (size_t)(m0+row)*K + k0 + sc),
                                     AS3(As + c*512), 16, 0, 0);
  }
#pragma unroll
  for (int i = 0; i < 2; i++) {
    int c = i*4 + w;
    int row = c*8 + srow;
    int sc = scol ^ ((row & 7) << 3);
    __builtin_amdgcn_global_load_lds(AS1C(Bw + (size_t)(n0+row)*K + k0 + sc),
                                     AS3(Bs + c*512), 16, 0, 0);
  }
}

__global__ __launch_bounds__(256) void gemm_bt(GemmArgs ga, int M, int N, int K)
{
  const int z = blockIdx.z;
  const bf16_t* __restrict__ A  = ga.A[z];
  const bf16_t* __restrict__ Bw = ga.W[z];
  const float*  __restrict__ bias = ga.bias[z];
  void* __restrict__ out = ga.out[z];
  const float scale = ga.scale[z];
  const int mode = ga.mode[z];

  __shared__ bf16_t As[2][BM*BKs];   // 2x16KB
  __shared__ bf16_t Bs[2][BN*BKs];   // 2x8KB
  const int tid = threadIdx.x;
  const int lane = tid & 63;
  const int w = tid >> 6;
  const int m0 = blockIdx.x * BM;
  const int n0 = blockIdx.y * BN;
  const int wr = (w >> 1) * 64, wc = (w & 1) * 32;
  const int lrow16 = lane & 15;
  const int kgrp = lane >> 4;
  const int srow = lane >> 3;
  const int scol = (lane & 7) * 8;

  f32x4 acc[4][2] = {};

  stage_tile(A, Bw, m0, n0, K, 0, As[0], Bs[0], w, srow, scol);

  const int KT = K / BKs;
  int cur = 0;
  for (int kt = 0; kt < KT; ++kt) {
    if (kt + 1 < KT) {
      stage_tile(A, Bw, m0, n0, K, (kt+1)*BKs, As[cur^1], Bs[cur^1], w, srow, scol);
      wait_vm6();              // tile kt done; kt+1 stays in flight
    } else {
      wait_vm0();
    }
    bar();                     // staging of [cur] visible to all waves
#pragma unroll
    for (int ks = 0; ks < 2; ++ks) {
      const int kbyte = ks*64 + kgrp*16;
      bf16x8 af[4], bfr[2];
#pragma unroll
      for (int m = 0; m < 4; m++) {
        int row = wr + m*16 + lrow16;
        af[m] = *(const bf16x8*)((const char*)As[cur] + row*128 + (kbyte ^ ((row & 7) << 4)));
      }
#pragma unroll
      for (int n = 0; n < 2; n++) {
        int row = wc + n*16 + lrow16;
        bfr[n] = *(const bf16x8*)((const char*)Bs[cur] + row*128 + (kbyte ^ ((row & 7) << 4)));
      }
#pragma unroll
      for (int m = 0; m < 4; m++)
#pragma unroll
        for (int n = 0; n < 2; n++)
          acc[m][n] = __builtin_amdgcn_mfma_f32_16x16x32_bf16(af[m], bfr[n], acc[m][n], 0, 0, 0);
    }
    bar();                     // all reads of [cur] complete before reuse
    cur ^= 1;
  }

#pragma unroll
  for (int m = 0; m < 4; m++)
#pragma unroll
    for (int n = 0; n < 2; n++) {
      const int row0 = m0 + wr + m*16 + kgrp*4;
      const int col  = n0 + wc + n*16 + lrow16;
      const float bcol = bias[col];
      if (mode == 2) {
        // V^T: (B,H,DK,L) — 4 consecutive l values pack to one 8B store
        int b = row0 >> 11, l0 = row0 & 2047;
        int h = col >> 6, dk = col & 63;
        ushort4 u;
        u.x = bfu((acc[m][n][0] + bcol) * scale);
        u.y = bfu((acc[m][n][1] + bcol) * scale);
        u.z = bfu((acc[m][n][2] + bcol) * scale);
        u.w = bfu((acc[m][n][3] + bcol) * scale);
        *(ushort4*)((unsigned short*)out + ((size_t)((b<<4) + h)*DKd + dk)*Ll + l0) = u;
      } else {
#pragma unroll
        for (int i = 0; i < 4; i++) {
          int row = row0 + i;
          float v = (acc[m][n][i] + bcol) * scale;
          if (mode == 1) {
            ((float*)out)[(size_t)row*N + col] = v;
          } else {
            int b = row >> 11, l = row & 2047;
            int h = col >> 6, dk = col & 63;
            ((unsigned short*)out)[((size_t)((b<<4) + h)*Ll + l)*DKd + dk] = bfu(v);
          }
        }
      }
    }
}

// ---------------- causal flash attention (round-6 verified, 48.5us) ----------------
// 512 blocks x 4 waves x 16 q-rows; uniform pairs (j, 31-j) = exactly 33 steps.
// Counted-vmcnt pipeline; K and V^T double-buffered in swizzled LDS; swapped
// QK^T, in-register softmax, l via MFMA vs ones, packed swizzled P->LDS.
#define KVB 64

__global__ __launch_bounds__(256) void attn_kernel(
    const bf16_t* __restrict__ Qh, const bf16_t* __restrict__ Kh,
    const bf16_t* __restrict__ VTg, unsigned short* __restrict__ Oa)
{
  const int id = blockIdx.x;                 // 0..511
  const int x = id & 7;                      // XCD pin
  const int rest = id >> 3;                  // 0..63
  const int hq = rest >> 4;                  // 0..3
  const int j  = rest & 15;                  // pair index: tiles j and 31-j
  const int bh = x + 8*hq;
  const int sA = j;                          // last step of phase A
  const int qtB = 31 - j;

  const int tid = threadIdx.x, lane = tid & 63, w = tid >> 6;
  const int r = lane & 15, g = lane >> 4;

  const bf16_t* Qp  = Qh  + (size_t)bh * Ll * DKd;
  const bf16_t* Kp  = Kh  + (size_t)bh * Ll * DKd;
  const bf16_t* VTp = VTg + (size_t)bh * Ll * DKd;   // [dk][l]

  __shared__ bf16_t Klds[2][64*64];   // 16KB, XOR-swizzled 128B rows
  __shared__ bf16_t Vlds[2][64*64];   // 16KB, V^T rows (dk), same swizzle
  __shared__ bf16_t Plds[4][16*64];   // 8KB, per-wave P rows (q), swizzled

  int q0 = j * 64;
  // Q fragments for both phases, hoisted
  bf16x8 qf[2], qB[2];
#pragma unroll
  for (int ks = 0; ks < 2; ++ks) {
    qf[ks] = *(const bf16x8*)(Qp + (size_t)(q0 + w*16 + r)*DKd + ks*32 + g*8);
    qB[ks] = *(const bf16x8*)(Qp + (size_t)(qtB*64 + w*16 + r)*DKd + ks*32 + g*8);
  }

  bf16x8 ones;
#pragma unroll
  for (int jj = 0; jj < 8; ++jj) ones[jj] = (bf16_t)1.0f;

  f32x4 accO[4] = {};
  f32x4 accL = {};
  float mrow = -1e30f;

  const int krow_l = lane >> 3;                        // 0..7
  const int kcol_l = ((lane & 7)*16) ^ (krow_l << 4);  // swizzled source byte
  char* Pw = (char*)&Plds[w][0];
  const int rsw = (r & 7) << 4;
  const int b_ = bh >> 4, h_ = bh & 15;

  auto pre_tiles = [&](int kv, int buf){
#pragma unroll
    for (int i = 0; i < 2; ++i) {
      int c = i*4 + w;
      __builtin_amdgcn_global_load_lds(
        AS1C((const char*)Kp + (size_t)(kv*KVB + c*8 + krow_l)*128 + kcol_l),
        AS3((char*)&Klds[buf][0] + c*1024), 16, 0, 0);
      __builtin_amdgcn_global_load_lds(
        AS1C((const char*)VTp + (size_t)(c*8 + krow_l)*4096 + kv*128 + kcol_l),
        AS3((char*)&Vlds[buf][0] + c*1024), 16, 0, 0);
    }
  };

  pre_tiles(0, 0);   // phase A, kv=0

  int cur = 0;
  for (int s = 0; s < 33; ++s) {
    if (s < 32) {
      int kv2 = (s < sA) ? s + 1 : s - sA;   // next step's kv (phase B restarts at 0)
      pre_tiles(kv2, cur^1);
      wait_vm4();                            // this step's tiles done; next in flight
    } else {
      wait_vm0();
    }
    bar();                                   // staging of [cur] visible to all waves

    const int kv0 = ((s <= sA) ? s : s - sA - 1) * KVB;

    // S^T = K Q^T : sv[n][i] = S[q=q0+w*16+r][kv = kv0 + n*16 + g*4 + i]
    const char* Kbase = (const char*)&Klds[cur][0];
    f32x4 sv[4] = {};
    __builtin_amdgcn_s_setprio(1);
#pragma unroll
    for (int ks = 0; ks < 2; ++ks) {
      const int kbyte = ks*64 + g*16;
#pragma unroll
      for (int n = 0; n < 4; ++n) {
        int row = n*16 + r;
        bf16x8 kf = *(const bf16x8*)(Kbase + row*128 + (kbyte ^ ((row & 7) << 4)));
        sv[n] = __builtin_amdgcn_mfma_f32_16x16x32_bf16(kf, qf[ks], sv[n], 0, 0, 0);
      }
    }
    __builtin_amdgcn_s_setprio(0);

    // causal mask: diagonal tiles only (end of each phase)
    if (s == sA || s == 32) {
      const int qg = q0 + w*16 + r;
#pragma unroll
      for (int n = 0; n < 4; ++n)
#pragma unroll
        for (int i = 0; i < 4; ++i)
          if (kv0 + n*16 + g*4 + i > qg) sv[n][i] = -1e30f;
    }

    // in-register online softmax (log2 domain, defer-max)
    float m0 = fmaxf(fmaxf(sv[0][0], sv[0][1]), sv[0][2]);
    float m1 = fmaxf(fmaxf(sv[0][3], sv[1][0]), sv[1][1]);
    float m2 = fmaxf(fmaxf(sv[1][2], sv[1][3]), sv[2][0]);
    float m3 = fmaxf(fmaxf(sv[2][1], sv[2][2]), sv[2][3]);
    float m4 = fmaxf(fmaxf(sv[3][0], sv[3][1]), sv[3][2]);
    float mx = fmaxf(fmaxf(fmaxf(m0, m1), m2), fmaxf(fmaxf(m3, m4), sv[3][3]));
    if (__any(mx > mrow + 8.f)) {
      mx = fmaxf(mx, __shfl_xor(mx, 16));
      mx = fmaxf(mx, __shfl_xor(mx, 32));
      float mnew = fmaxf(mrow, mx);
      float corr = __builtin_amdgcn_exp2f(mrow - mnew);
      float c0 = __shfl(corr, g*4 + 0);
      float c1 = __shfl(corr, g*4 + 1);
      float c2 = __shfl(corr, g*4 + 2);
      float c3 = __shfl(corr, g*4 + 3);
#pragma unroll
      for (int n = 0; n < 4; ++n) {
        accO[n][0] *= c0; accO[n][1] *= c1; accO[n][2] *= c2; accO[n][3] *= c3;
      }
      accL[0] *= c0; accL[1] *= c1; accL[2] *= c2; accL[3] *= c3;
      mrow = mnew;
    }
#pragma unroll
    for (int n = 0; n < 4; ++n)
#pragma unroll
      for (int i = 0; i < 4; ++i)
        sv[n][i] = __builtin_amdgcn_exp2f(sv[n][i] - mrow);

    // pack P -> per-wave LDS: 4 x b64 swizzled writes (same-wave, no barrier)
#pragma unroll
    for (int n = 0; n < 4; ++n) {
      unsigned lo = (unsigned)bfu(sv[n][0]) | ((unsigned)bfu(sv[n][1]) << 16);
      unsigned hi = (unsigned)bfu(sv[n][2]) | ((unsigned)bfu(sv[n][3]) << 16);
      u32x2 pk; pk[0] = lo; pk[1] = hi;
      *(u32x2*)(Pw + r*128 + ((n*32 + g*8) ^ rsw)) = pk;
    }

    // PV: O += P * V, l += P * 1
    const char* Vbase = (const char*)&Vlds[cur][0];
    __builtin_amdgcn_s_setprio(1);
#pragma unroll
    for (int ks = 0; ks < 2; ++ks) {
      const int kbyte = ks*64 + g*16;
      bf16x8 pa = *(const bf16x8*)(Pw + r*128 + (kbyte ^ rsw));
      accL = __builtin_amdgcn_mfma_f32_16x16x32_bf16(pa, ones, accL, 0, 0, 0);
#pragma unroll
      for (int n = 0; n < 4; ++n) {
        int row = n*16 + r;
        bf16x8 vf = *(const bf16x8*)(Vbase + row*128 + (kbyte ^ ((row & 7) << 4)));
        accO[n] = __builtin_amdgcn_mfma_f32_16x16x32_bf16(pa, vf, accO[n], 0, 0, 0);
      }
    }
    __builtin_amdgcn_s_setprio(0);

    // phase A finished: store, reset, switch to tile B's Q
    if (s == sA) {
#pragma unroll
      for (int i = 0; i < 4; ++i) {
        float inv = 1.f / accL[i];
        int q = q0 + w*16 + g*4 + i;
#pragma unroll
        for (int n = 0; n < 4; ++n)
          Oa[((size_t)(b_*Ll + q))*Dd + h_*DKd + n*16 + r] = bfu(accO[n][i] * inv);
      }
      q0 = qtB * 64;
      qf[0] = qB[0]; qf[1] = qB[1];
#pragma unroll
      for (int n = 0; n < 4; ++n) accO[n] = f32x4{};
      accL = f32x4{};
      mrow = -1e30f;
    }

    bar();                                   // all reads of [cur] done before reuse
    cur ^= 1;
  }

  // phase B store
#pragma unroll
  for (int i = 0; i < 4; ++i) {
    float inv = 1.f / accL[i];
    int q = q0 + w*16 + g*4 + i;
#pragma unroll
    for (int n = 0; n < 4; ++n)
      Oa[((size_t)(b_*Ll + q))*Dd + h_*DKd + n*16 + r] = bfu(accO[n][i] * inv);
  }
}

// ---------------- launch ----------------
extern "C" void kernel_launch(void* const* d_in, const int* in_sizes, int n_in,
                              void* d_out, int out_size, void* d_ws, size_t ws_size,
                              hipStream_t stream)
{
  const float* q  = (const float*)d_in[0];
  const float* k  = (const float*)d_in[1];
  const float* v  = (const float*)d_in[2];
  // d_in[3] = mask (causal, hardcoded)
  const float* wq = (const float*)d_in[4];
  const float* bq = (const float*)d_in[5];
  const float* wk = (const float*)d_in[6];
  const float* bk = (const float*)d_in[7];
  const float* wv = (const float*)d_in[8];
  const float* bv = (const float*)d_in[9];
  const float* wo = (const float*)d_in[10];
  const float* bo = (const float*)d_in[11];

  char* ws = (char*)d_ws;
  bf16_t* Xq = (bf16_t*)(ws + 0);
  bf16_t* Xk = (bf16_t*)(ws + 8388608);
  bf16_t* Xv = (bf16_t*)(ws + 16777216);
  bf16_t* Wq = (bf16_t*)(ws + 25165824);
  bf16_t* Wk = (bf16_t*)(ws + 27262976);
  bf16_t* Wv = (bf16_t*)(ws + 29360128);
  bf16_t* Wo = (bf16_t*)(ws + 31457280);
  bf16_t* Qh = (bf16_t*)(ws + 33554432);
  bf16_t* Kh = (bf16_t*)(ws + 41943040);
  bf16_t* VT = (bf16_t*)(ws + 50331648);   // V^T (B,H,DK,L), written by V-GEMM
  bf16_t* Oa = (bf16_t*)(ws + 58720256);   // total 64 MiB

  const int NX4 = Mm * Dd / 4;   // 1048576
  const int NW4 = Dd * Dd / 4;   // 262144

  Cvt7 cv;
  cv.in[0]=q;  cv.out[0]=(ushort4*)Xq; cv.n4[0]=NX4;
  cv.in[1]=k;  cv.out[1]=(ushort4*)Xk; cv.n4[1]=NX4;
  cv.in[2]=v;  cv.out[2]=(ushort4*)Xv; cv.n4[2]=NX4;
  cv.in[3]=wq; cv.out[3]=(ushort4*)Wq; cv.n4[3]=NW4;
  cv.in[4]=wk; cv.out[4]=(ushort4*)Wk; cv.n4[4]=NW4;
  cv.in[5]=wv; cv.out[5]=(ushort4*)Wv; cv.n4[5]=NW4;
  cv.in[6]=wo; cv.out[6]=(ushort4*)Wo; cv.n4[6]=NW4;
  cvt_multi<<<dim3(NX4/256, 7), 256, 0, stream>>>(cv);

  const float qscale = 0.125f * 1.4426950408889634f;  // 1/sqrt(DK) * log2(e)
  GemmArgs gqkv;
  gqkv.A[0]=Xq; gqkv.A[1]=Xk; gqkv.A[2]=Xv;
  gqkv.W[0]=Wq; gqkv.W[1]=Wk; gqkv.W[2]=Wv;
  gqkv.bias[0]=bq; gqkv.bias[1]=bk; gqkv.bias[2]=bv;
  gqkv.out[0]=Qh; gqkv.out[1]=Kh; gqkv.out[2]=VT;
  gqkv.scale[0]=qscale; gqkv.scale[1]=1.0f; gqkv.scale[2]=1.0f;
  gqkv.mode[0]=0; gqkv.mode[1]=0; gqkv.mode[2]=2;     // V writes V^T directly
  gemm_bt<<<dim3(Mm/BM, Dd/BN, 3), 256, 0, stream>>>(gqkv, Mm, Dd, Dd);

  attn_kernel<<<dim3(512), 256, 0, stream>>>(Qh, Kh, VT, (unsigned short*)Oa);

  GemmArgs go;
  go.A[0]=Oa; go.A[1]=Oa; go.A[2]=Oa;
  go.W[0]=Wo; go.W[1]=Wo; go.W[2]=Wo;
  go.bias[0]=bo; go.bias[1]=bo; go.bias[2]=bo;
  go.out[0]=d_out; go.out[1]=d_out; go.out[2]=d_out;
  go.scale[0]=1.0f; go.scale[1]=1.0f; go.scale[2]=1.0f;
  go.mode[0]=1; go.mode[1]=1; go.mode[2]=1;
  gemm_bt<<<dim3(Mm/BM, Dd/BN, 1), 256, 0, stream>>>(go, Mm, Dd, Dd);
}

// Round 12
// 113.649 us; speedup vs baseline: 1.2521x; 1.0319x over previous
//
#include <hip/hip_runtime.h>
#include <stdint.h>

#define Bb 2
#define Ll 2048
#define Dd 1024
#define Hh 16
#define DKd 64
#define Mm (Bb*Ll)   // 4096

typedef __bf16 bf16_t;
typedef __bf16 bf16x8 __attribute__((ext_vector_type(8)));
typedef float f32x4 __attribute__((ext_vector_type(4)));
typedef unsigned u32x2 __attribute__((ext_vector_type(2)));

#define AS1C(p) ((const __attribute__((address_space(1))) void*)(p))
#define AS3(p)  ((__attribute__((address_space(3))) void*)(p))

__device__ __forceinline__ unsigned short bfu(float f){
  return __builtin_bit_cast(unsigned short, (bf16_t)f);   // native v_cvt, RTNE
}
__device__ __forceinline__ void wait_vm4(){ asm volatile("s_waitcnt vmcnt(4)" ::: "memory"); }
__device__ __forceinline__ void wait_vm6(){ asm volatile("s_waitcnt vmcnt(6)" ::: "memory"); }
__device__ __forceinline__ void wait_vm0(){ asm volatile("s_waitcnt vmcnt(0)" ::: "memory"); }
__device__ __forceinline__ void bar(){
  __builtin_amdgcn_sched_barrier(0);
  __builtin_amdgcn_s_barrier();
  __builtin_amdgcn_sched_barrier(0);
}

// ---------------- fp32 -> bf16 convert: all 7 buffers, one launch ----------------
struct Cvt7 { const float* in[7]; ushort4* out[7]; int n4[7]; };

__global__ void cvt_multi(Cvt7 a){
  const int z = blockIdx.y;
  int i = blockIdx.x*256 + threadIdx.x;
  if (i < a.n4[z]){
    float4 v = ((const float4*)a.in[z])[i];
    ushort4 o; o.x=bfu(v.x); o.y=bfu(v.y); o.z=bfu(v.z); o.w=bfu(v.w);
    a.out[z][i] = o;
  }
}

// ---------------- shared GEMM pieces ----------------
struct GemmArgs {
  const bf16_t* A[3];
  const bf16_t* W[3];
  const float*  bias[3];
  void*         out[3];
  float         scale[3];
  int           mode[3];   // 0: bf16 (B,H,L,DK); 1: fp32 row-major; 2: bf16 V^T (B,H,DK,L)
};

// ---------------- QKV GEMM: m97-structure 128x128, single-buffer ----------------
#define BKs 64

__global__ __launch_bounds__(256) void gemm128(GemmArgs ga, int M, int N, int K)
{
  const int z = blockIdx.z;
  const bf16_t* __restrict__ A  = ga.A[z];
  const bf16_t* __restrict__ Bw = ga.W[z];
  const float*  __restrict__ bias = ga.bias[z];
  void* __restrict__ out = ga.out[z];
  const float scale = ga.scale[z];
  const int mode = ga.mode[z];

  __shared__ bf16_t As[128*BKs];   // 16KB
  __shared__ bf16_t Bs[128*BKs];   // 16KB
  const int tid = threadIdx.x;
  const int lane = tid & 63;
  const int w = tid >> 6;
  const int m0 = blockIdx.x * 128;
  const int n0 = blockIdx.y * 128;
  const int wr = (w >> 1) * 64, wc = (w & 1) * 64;
  const int lrow16 = lane & 15;
  const int kgrp = lane >> 4;
  const int srow = lane >> 3;
  const int scol = (lane & 7) * 8;

  f32x4 acc[4][4] = {};

  for (int k0 = 0; k0 < K; k0 += BKs) {
#pragma unroll
    for (int i = 0; i < 4; i++) {
      int c = i*4 + w;
      int row = c*8 + srow;
      int sc = scol ^ ((row & 7) << 3);   // inverse-swizzled global source
      __builtin_amdgcn_global_load_lds(AS1C(A + (size_t)(m0+row)*K + k0 + sc),
                                       AS3(As + c*512), 16, 0, 0);
    }
#pragma unroll
    for (int i = 0; i < 4; i++) {
      int c = i*4 + w;
      int row = c*8 + srow;
      int sc = scol ^ ((row & 7) << 3);
      __builtin_amdgcn_global_load_lds(AS1C(Bw + (size_t)(n0+row)*K + k0 + sc),
                                       AS3(Bs + c*512), 16, 0, 0);
    }
    __syncthreads();
#pragma unroll
    for (int ks = 0; ks < 2; ++ks) {
      const int kbyte = ks*64 + kgrp*16;
      bf16x8 af[4], bfr[4];
#pragma unroll
      for (int m = 0; m < 4; m++) {
        int row = wr + m*16 + lrow16;
        af[m] = *(const bf16x8*)((const char*)As + row*128 + (kbyte ^ ((row & 7) << 4)));
      }
#pragma unroll
      for (int n = 0; n < 4; n++) {
        int row = wc + n*16 + lrow16;
        bfr[n] = *(const bf16x8*)((const char*)Bs + row*128 + (kbyte ^ ((row & 7) << 4)));
      }
#pragma unroll
      for (int m = 0; m < 4; m++)
#pragma unroll
        for (int n = 0; n < 4; n++)
          acc[m][n] = __builtin_amdgcn_mfma_f32_16x16x32_bf16(af[m], bfr[n], acc[m][n], 0, 0, 0);
    }
    __syncthreads();
  }

#pragma unroll
  for (int m = 0; m < 4; m++)
#pragma unroll
    for (int n = 0; n < 4; n++) {
      const int row0 = m0 + wr + m*16 + kgrp*4;
      const int col  = n0 + wc + n*16 + lrow16;
      const float bcol = bias[col];
      if (mode == 2) {
        int b = row0 >> 11, l0 = row0 & 2047;
        int h = col >> 6, dk = col & 63;
        ushort4 u;
        u.x = bfu((acc[m][n][0] + bcol) * scale);
        u.y = bfu((acc[m][n][1] + bcol) * scale);
        u.z = bfu((acc[m][n][2] + bcol) * scale);
        u.w = bfu((acc[m][n][3] + bcol) * scale);
        *(ushort4*)((unsigned short*)out + ((size_t)((b<<4) + h)*DKd + dk)*Ll + l0) = u;
      } else {
#pragma unroll
        for (int i = 0; i < 4; i++) {
          int row = row0 + i;
          float v = (acc[m][n][i] + bcol) * scale;
          if (mode == 1) {
            ((float*)out)[(size_t)row*N + col] = v;
          } else {
            int b = row >> 11, l = row & 2047;
            int h = col >> 6, dk = col & 63;
            ((unsigned short*)out)[((size_t)((b<<4) + h)*Ll + l)*DKd + dk] = bfu(v);
          }
        }
      }
    }
}

// ---------------- O GEMM: BN=64 counted-vmcnt dbuf (round-11 verified) ----------------
#define BM 128
#define BN 64

__device__ __forceinline__ void stage_tile(
    const bf16_t* __restrict__ A, const bf16_t* __restrict__ Bw,
    int m0, int n0, int K, int k0, bf16_t* As, bf16_t* Bs,
    int w, int srow, int scol)
{
#pragma unroll
  for (int i = 0; i < 4; i++) {
    int c = i*4 + w;
    int row = c*8 + srow;
    int sc = scol ^ ((row & 7) << 3);
    __builtin_amdgcn_global_load_lds(AS1C(A + (size_t)(m0+row)*K + k0 + sc),
                                     AS3(As + c*512), 16, 0, 0);
  }
#pragma unroll
  for (int i = 0; i < 2; i++) {
    int c = i*4 + w;
    int row = c*8 + srow;
    int sc = scol ^ ((row & 7) << 3);
    __builtin_amdgcn_global_load_lds(AS1C(Bw + (size_t)(n0+row)*K + k0 + sc),
                                     AS3(Bs + c*512), 16, 0, 0);
  }
}

__global__ __launch_bounds__(256) void gemm_bt(GemmArgs ga, int M, int N, int K)
{
  const int z = blockIdx.z;
  const bf16_t* __restrict__ A  = ga.A[z];
  const bf16_t* __restrict__ Bw = ga.W[z];
  const float*  __restrict__ bias = ga.bias[z];
  void* __restrict__ out = ga.out[z];
  const float scale = ga.scale[z];
  const int mode = ga.mode[z];

  __shared__ bf16_t As[2][BM*BKs];   // 2x16KB
  __shared__ bf16_t Bs[2][BN*BKs];   // 2x8KB
  const int tid = threadIdx.x;
  const int lane = tid & 63;
  const int w = tid >> 6;
  const int m0 = blockIdx.x * BM;
  const int n0 = blockIdx.y * BN;
  const int wr = (w >> 1) * 64, wc = (w & 1) * 32;
  const int lrow16 = lane & 15;
  const int kgrp = lane >> 4;
  const int srow = lane >> 3;
  const int scol = (lane & 7) * 8;

  f32x4 acc[4][2] = {};

  stage_tile(A, Bw, m0, n0, K, 0, As[0], Bs[0], w, srow, scol);

  const int KT = K / BKs;
  int cur = 0;
  for (int kt = 0; kt < KT; ++kt) {
    if (kt + 1 < KT) {
      stage_tile(A, Bw, m0, n0, K, (kt+1)*BKs, As[cur^1], Bs[cur^1], w, srow, scol);
      wait_vm6();
    } else {
      wait_vm0();
    }
    bar();
#pragma unroll
    for (int ks = 0; ks < 2; ++ks) {
      const int kbyte = ks*64 + kgrp*16;
      bf16x8 af[4], bfr[2];
#pragma unroll
      for (int m = 0; m < 4; m++) {
        int row = wr + m*16 + lrow16;
        af[m] = *(const bf16x8*)((const char*)As[cur] + row*128 + (kbyte ^ ((row & 7) << 4)));
      }
#pragma unroll
      for (int n = 0; n < 2; n++) {
        int row = wc + n*16 + lrow16;
        bfr[n] = *(const bf16x8*)((const char*)Bs[cur] + row*128 + (kbyte ^ ((row & 7) << 4)));
      }
#pragma unroll
      for (int m = 0; m < 4; m++)
#pragma unroll
        for (int n = 0; n < 2; n++)
          acc[m][n] = __builtin_amdgcn_mfma_f32_16x16x32_bf16(af[m], bfr[n], acc[m][n], 0, 0, 0);
    }
    bar();
    cur ^= 1;
  }

#pragma unroll
  for (int m = 0; m < 4; m++)
#pragma unroll
    for (int n = 0; n < 2; n++) {
      const int row0 = m0 + wr + m*16 + kgrp*4;
      const int col  = n0 + wc + n*16 + lrow16;
      const float bcol = bias[col];
      if (mode == 2) {
        int b = row0 >> 11, l0 = row0 & 2047;
        int h = col >> 6, dk = col & 63;
        ushort4 u;
        u.x = bfu((acc[m][n][0] + bcol) * scale);
        u.y = bfu((acc[m][n][1] + bcol) * scale);
        u.z = bfu((acc[m][n][2] + bcol) * scale);
        u.w = bfu((acc[m][n][3] + bcol) * scale);
        *(ushort4*)((unsigned short*)out + ((size_t)((b<<4) + h)*DKd + dk)*Ll + l0) = u;
      } else {
#pragma unroll
        for (int i = 0; i < 4; i++) {
          int row = row0 + i;
          float v = (acc[m][n][i] + bcol) * scale;
          if (mode == 1) {
            ((float*)out)[(size_t)row*N + col] = v;
          } else {
            int b = row >> 11, l = row & 2047;
            int h = col >> 6, dk = col & 63;
            ((unsigned short*)out)[((size_t)((b<<4) + h)*Ll + l)*DKd + dk] = bfu(v);
          }
        }
      }
    }
}

// ---------------- causal flash attention (round-11 verified, 48.5us) ----------------
#define KVB 64

__global__ __launch_bounds__(256) void attn_kernel(
    const bf16_t* __restrict__ Qh, const bf16_t* __restrict__ Kh,
    const bf16_t* __restrict__ VTg, unsigned short* __restrict__ Oa)
{
  const int id = blockIdx.x;                 // 0..511
  const int x = id & 7;                      // XCD pin
  const int rest = id >> 3;                  // 0..63
  const int hq = rest >> 4;                  // 0..3
  const int j  = rest & 15;                  // pair index: tiles j and 31-j
  const int bh = x + 8*hq;
  const int sA = j;                          // last step of phase A
  const int qtB = 31 - j;

  const int tid = threadIdx.x, lane = tid & 63, w = tid >> 6;
  const int r = lane & 15, g = lane >> 4;

  const bf16_t* Qp  = Qh  + (size_t)bh * Ll * DKd;
  const bf16_t* Kp  = Kh  + (size_t)bh * Ll * DKd;
  const bf16_t* VTp = VTg + (size_t)bh * Ll * DKd;   // [dk][l]

  __shared__ bf16_t Klds[2][64*64];   // 16KB, XOR-swizzled 128B rows
  __shared__ bf16_t Vlds[2][64*64];   // 16KB, V^T rows (dk), same swizzle
  __shared__ bf16_t Plds[4][16*64];   // 8KB, per-wave P rows (q), swizzled

  int q0 = j * 64;
  bf16x8 qf[2], qB[2];
#pragma unroll
  for (int ks = 0; ks < 2; ++ks) {
    qf[ks] = *(const bf16x8*)(Qp + (size_t)(q0 + w*16 + r)*DKd + ks*32 + g*8);
    qB[ks] = *(const bf16x8*)(Qp + (size_t)(qtB*64 + w*16 + r)*DKd + ks*32 + g*8);
  }

  bf16x8 ones;
#pragma unroll
  for (int jj = 0; jj < 8; ++jj) ones[jj] = (bf16_t)1.0f;

  f32x4 accO[4] = {};
  f32x4 accL = {};
  float mrow = -1e30f;

  const int krow_l = lane >> 3;                        // 0..7
  const int kcol_l = ((lane & 7)*16) ^ (krow_l << 4);  // swizzled source byte
  char* Pw = (char*)&Plds[w][0];
  const int rsw = (r & 7) << 4;
  const int b_ = bh >> 4, h_ = bh & 15;

  auto pre_tiles = [&](int kv, int buf){
#pragma unroll
    for (int i = 0; i < 2; ++i) {
      int c = i*4 + w;
      __builtin_amdgcn_global_load_lds(
        AS1C((const char*)Kp + (size_t)(kv*KVB + c*8 + krow_l)*128 + kcol_l),
        AS3((char*)&Klds[buf][0] + c*1024), 16, 0, 0);
      __builtin_amdgcn_global_load_lds(
        AS1C((const char*)VTp + (size_t)(c*8 + krow_l)*4096 + kv*128 + kcol_l),
        AS3((char*)&Vlds[buf][0] + c*1024), 16, 0, 0);
    }
  };

  pre_tiles(0, 0);   // phase A, kv=0

  int cur = 0;
  for (int s = 0; s < 33; ++s) {
    if (s < 32) {
      int kv2 = (s < sA) ? s + 1 : s - sA;   // next step's kv (phase B restarts at 0)
      pre_tiles(kv2, cur^1);
      wait_vm4();                            // this step's tiles done; next in flight
    } else {
      wait_vm0();
    }
    bar();                                   // staging of [cur] visible to all waves

    const int kv0 = ((s <= sA) ? s : s - sA - 1) * KVB;

    // S^T = K Q^T : sv[n][i] = S[q=q0+w*16+r][kv = kv0 + n*16 + g*4 + i]
    const char* Kbase = (const char*)&Klds[cur][0];
    f32x4 sv[4] = {};
    __builtin_amdgcn_s_setprio(1);
#pragma unroll
    for (int ks = 0; ks < 2; ++ks) {
      const int kbyte = ks*64 + g*16;
#pragma unroll
      for (int n = 0; n < 4; ++n) {
        int row = n*16 + r;
        bf16x8 kf = *(const bf16x8*)(Kbase + row*128 + (kbyte ^ ((row & 7) << 4)));
        sv[n] = __builtin_amdgcn_mfma_f32_16x16x32_bf16(kf, qf[ks], sv[n], 0, 0, 0);
      }
    }
    __builtin_amdgcn_s_setprio(0);

    // causal mask: diagonal tiles only (end of each phase)
    if (s == sA || s == 32) {
      const int qg = q0 + w*16 + r;
#pragma unroll
      for (int n = 0; n < 4; ++n)
#pragma unroll
        for (int i = 0; i < 4; ++i)
          if (kv0 + n*16 + g*4 + i > qg) sv[n][i] = -1e30f;
    }

    // in-register online softmax (log2 domain, defer-max)
    float m0 = fmaxf(fmaxf(sv[0][0], sv[0][1]), sv[0][2]);
    float m1 = fmaxf(fmaxf(sv[0][3], sv[1][0]), sv[1][1]);
    float m2 = fmaxf(fmaxf(sv[1][2], sv[1][3]), sv[2][0]);
    float m3 = fmaxf(fmaxf(sv[2][1], sv[2][2]), sv[2][3]);
    float m4 = fmaxf(fmaxf(sv[3][0], sv[3][1]), sv[3][2]);
    float mx = fmaxf(fmaxf(fmaxf(m0, m1), m2), fmaxf(fmaxf(m3, m4), sv[3][3]));
    if (__any(mx > mrow + 8.f)) {
      mx = fmaxf(mx, __shfl_xor(mx, 16));
      mx = fmaxf(mx, __shfl_xor(mx, 32));
      float mnew = fmaxf(mrow, mx);
      float corr = __builtin_amdgcn_exp2f(mrow - mnew);
      float c0 = __shfl(corr, g*4 + 0);
      float c1 = __shfl(corr, g*4 + 1);
      float c2 = __shfl(corr, g*4 + 2);
      float c3 = __shfl(corr, g*4 + 3);
#pragma unroll
      for (int n = 0; n < 4; ++n) {
        accO[n][0] *= c0; accO[n][1] *= c1; accO[n][2] *= c2; accO[n][3] *= c3;
      }
      accL[0] *= c0; accL[1] *= c1; accL[2] *= c2; accL[3] *= c3;
      mrow = mnew;
    }
#pragma unroll
    for (int n = 0; n < 4; ++n)
#pragma unroll
      for (int i = 0; i < 4; ++i)
        sv[n][i] = __builtin_amdgcn_exp2f(sv[n][i] - mrow);

    // pack P -> per-wave LDS: 4 x b64 swizzled writes (same-wave, no barrier)
#pragma unroll
    for (int n = 0; n < 4; ++n) {
      unsigned lo = (unsigned)bfu(sv[n][0]) | ((unsigned)bfu(sv[n][1]) << 16);
      unsigned hi = (unsigned)bfu(sv[n][2]) | ((unsigned)bfu(sv[n][3]) << 16);
      u32x2 pk; pk[0] = lo; pk[1] = hi;
      *(u32x2*)(Pw + r*128 + ((n*32 + g*8) ^ rsw)) = pk;
    }

    // PV: O += P * V, l += P * 1
    const char* Vbase = (const char*)&Vlds[cur][0];
    __builtin_amdgcn_s_setprio(1);
#pragma unroll
    for (int ks = 0; ks < 2; ++ks) {
      const int kbyte = ks*64 + g*16;
      bf16x8 pa = *(const bf16x8*)(Pw + r*128 + (kbyte ^ rsw));
      accL = __builtin_amdgcn_mfma_f32_16x16x32_bf16(pa, ones, accL, 0, 0, 0);
#pragma unroll
      for (int n = 0; n < 4; ++n) {
        int row = n*16 + r;
        bf16x8 vf = *(const bf16x8*)(Vbase + row*128 + (kbyte ^ ((row & 7) << 4)));
        accO[n] = __builtin_amdgcn_mfma_f32_16x16x32_bf16(pa, vf, accO[n], 0, 0, 0);
      }
    }
    __builtin_amdgcn_s_setprio(0);

    // phase A finished: store, reset, switch to tile B's Q
    if (s == sA) {
#pragma unroll
      for (int i = 0; i < 4; ++i) {
        float inv = 1.f / accL[i];
        int q = q0 + w*16 + g*4 + i;
#pragma unroll
        for (int n = 0; n < 4; ++n)
          Oa[((size_t)(b_*Ll + q))*Dd + h_*DKd + n*16 + r] = bfu(accO[n][i] * inv);
      }
      q0 = qtB * 64;
      qf[0] = qB[0]; qf[1] = qB[1];
#pragma unroll
      for (int n = 0; n < 4; ++n) accO[n] = f32x4{};
      accL = f32x4{};
      mrow = -1e30f;
    }

    bar();                                   // all reads of [cur] done before reuse
    cur ^= 1;
  }

  // phase B store
#pragma unroll
  for (int i = 0; i < 4; ++i) {
    float inv = 1.f / accL[i];
    int q = q0 + w*16 + g*4 + i;
#pragma unroll
    for (int n = 0; n < 4; ++n)
      Oa[((size_t)(b_*Ll + q))*Dd + h_*DKd + n*16 + r] = bfu(accO[n][i] * inv);
  }
}

// ---------------- launch ----------------
extern "C" void kernel_launch(void* const* d_in, const int* in_sizes, int n_in,
                              void* d_out, int out_size, void* d_ws, size_t ws_size,
                              hipStream_t stream)
{
  const float* q  = (const float*)d_in[0];
  const float* k  = (const float*)d_in[1];
  const float* v  = (const float*)d_in[2];
  // d_in[3] = mask (causal, hardcoded)
  const float* wq = (const float*)d_in[4];
  const float* bq = (const float*)d_in[5];
  const float* wk = (const float*)d_in[6];
  const float* bk = (const float*)d_in[7];
  const float* wv = (const float*)d_in[8];
  const float* bv = (const float*)d_in[9];
  const float* wo = (const float*)d_in[10];
  const float* bo = (const float*)d_in[11];

  char* ws = (char*)d_ws;
  bf16_t* Xq = (bf16_t*)(ws + 0);
  bf16_t* Xk = (bf16_t*)(ws + 8388608);
  bf16_t* Xv = (bf16_t*)(ws + 16777216);
  bf16_t* Wq = (bf16_t*)(ws + 25165824);
  bf16_t* Wk = (bf16_t*)(ws + 27262976);
  bf16_t* Wv = (bf16_t*)(ws + 29360128);
  bf16_t* Wo = (bf16_t*)(ws + 31457280);
  bf16_t* Qh = (bf16_t*)(ws + 33554432);
  bf16_t* Kh = (bf16_t*)(ws + 41943040);
  bf16_t* VT = (bf16_t*)(ws + 50331648);   // V^T (B,H,DK,L), written by V-GEMM
  bf16_t* Oa = (bf16_t*)(ws + 58720256);   // total 64 MiB

  const int NX4 = Mm * Dd / 4;   // 1048576
  const int NW4 = Dd * Dd / 4;   // 262144

  Cvt7 cv;
  cv.in[0]=q;  cv.out[0]=(ushort4*)Xq; cv.n4[0]=NX4;
  cv.in[1]=k;  cv.out[1]=(ushort4*)Xk; cv.n4[1]=NX4;
  cv.in[2]=v;  cv.out[2]=(ushort4*)Xv; cv.n4[2]=NX4;
  cv.in[3]=wq; cv.out[3]=(ushort4*)Wq; cv.n4[3]=NW4;
  cv.in[4]=wk; cv.out[4]=(ushort4*)Wk; cv.n4[4]=NW4;
  cv.in[5]=wv; cv.out[5]=(ushort4*)Wv; cv.n4[5]=NW4;
  cv.in[6]=wo; cv.out[6]=(ushort4*)Wo; cv.n4[6]=NW4;
  cvt_multi<<<dim3(NX4/256, 7), 256, 0, stream>>>(cv);

  const float qscale = 0.125f * 1.4426950408889634f;  // 1/sqrt(DK) * log2(e)
  GemmArgs gqkv;
  gqkv.A[0]=Xq; gqkv.A[1]=Xk; gqkv.A[2]=Xv;
  gqkv.W[0]=Wq; gqkv.W[1]=Wk; gqkv.W[2]=Wv;
  gqkv.bias[0]=bq; gqkv.bias[1]=bk; gqkv.bias[2]=bv;
  gqkv.out[0]=Qh; gqkv.out[1]=Kh; gqkv.out[2]=VT;
  gqkv.scale[0]=qscale; gqkv.scale[1]=1.0f; gqkv.scale[2]=1.0f;
  gqkv.mode[0]=0; gqkv.mode[1]=0; gqkv.mode[2]=2;     // V writes V^T directly
  gemm128<<<dim3(Mm/128, Dd/128, 3), 256, 0, stream>>>(gqkv, Mm, Dd, Dd);  // 768 = 3/CU

  attn_kernel<<<dim3(512), 256, 0, stream>>>(Qh, Kh, VT, (unsigned short*)Oa);

  GemmArgs go;
  go.A[0]=Oa; go.A[1]=Oa; go.A[2]=Oa;
  go.W[0]=Wo; go.W[1]=Wo; go.W[2]=Wo;
  go.bias[0]=bo; go.bias[1]=bo; go.bias[2]=bo;
  go.out[0]=d_out; go.out[1]=d_out; go.out[2]=d_out;
  go.scale[0]=1.0f; go.scale[1]=1.0f; go.scale[2]=1.0f;
  go.mode[0]=1; go.mode[1]=1; go.mode[2]=1;
  gemm_bt<<<dim3(Mm/BM, Dd/BN, 1), 256, 0, stream>>>(go, Mm, Dd, Dd);
}

// Round 13
// 109.558 us; speedup vs baseline: 1.2988x; 1.0373x over previous
//
#include <hip/hip_runtime.h>
#include <stdint.h>

#define Bb 2
#define Ll 2048
#define Dd 1024
#define Hh 16
#define DKd 64
#define Mm (Bb*Ll)   // 4096

typedef __bf16 bf16_t;
typedef __bf16 bf16x8 __attribute__((ext_vector_type(8)));
typedef float f32x4 __attribute__((ext_vector_type(4)));
typedef unsigned u32x2 __attribute__((ext_vector_type(2)));

#define AS1C(p) ((const __attribute__((address_space(1))) void*)(p))
#define AS3(p)  ((__attribute__((address_space(3))) void*)(p))

__device__ __forceinline__ unsigned short bfu(float f){
  return __builtin_bit_cast(unsigned short, (bf16_t)f);   // native v_cvt, RTNE
}
__device__ __forceinline__ void wait_vm4(){ asm volatile("s_waitcnt vmcnt(4)" ::: "memory"); }
__device__ __forceinline__ void wait_vm6(){ asm volatile("s_waitcnt vmcnt(6)" ::: "memory"); }
__device__ __forceinline__ void wait_vm0(){ asm volatile("s_waitcnt vmcnt(0)" ::: "memory"); }
__device__ __forceinline__ void bar(){
  __builtin_amdgcn_sched_barrier(0);
  __builtin_amdgcn_s_barrier();
  __builtin_amdgcn_sched_barrier(0);
}

// ---------------- fp32 -> bf16 convert: weights only ----------------
struct Cvt4 { const float* in[4]; ushort4* out[4]; };

__global__ void cvt_multi(Cvt4 a, int n4){
  const int z = blockIdx.y;
  int i = blockIdx.x*256 + threadIdx.x;
  if (i < n4){
    float4 v = ((const float4*)a.in[z])[i];
    ushort4 o; o.x=bfu(v.x); o.y=bfu(v.y); o.z=bfu(v.z); o.w=bfu(v.w);
    a.out[z][i] = o;
  }
}

// ---------------- shared GEMM pieces ----------------
struct GemmArgs {
  const void*   A[3];    // fp32 for gemm128_f32, bf16 for gemm_bt
  const bf16_t* W[3];
  const float*  bias[3];
  void*         out[3];
  float         scale[3];
  int           mode[3];   // 0: bf16 (B,H,L,DK); 1: fp32 row-major; 2: bf16 V^T (B,H,DK,L)
};

// ---------------- QKV GEMM: 128x128, A staged as FP32 (in-GEMM convert) ----------------
#define BKs 64

__global__ __launch_bounds__(256) void gemm128_f32(GemmArgs ga, int M, int N, int K)
{
  const int z = blockIdx.z;
  const float*  __restrict__ A  = (const float*)ga.A[z];
  const bf16_t* __restrict__ Bw = ga.W[z];
  const float*  __restrict__ bias = ga.bias[z];
  void* __restrict__ out = ga.out[z];
  const float scale = ga.scale[z];
  const int mode = ga.mode[z];

  __shared__ float  As[128*BKs];   // 32KB fp32, rows of 256B, XOR-swizzled
  __shared__ bf16_t Bs[128*BKs];   // 16KB bf16, rows of 128B, XOR-swizzled
  const int tid = threadIdx.x;
  const int lane = tid & 63;
  const int w = tid >> 6;
  const int m0 = blockIdx.x * 128;
  const int n0 = blockIdx.y * 128;
  const int wr = (w >> 1) * 64, wc = (w & 1) * 64;
  const int lrow16 = lane & 15;
  const int kgrp = lane >> 4;

  // A-staging lane constants: 1KB chunks of 4 rows (fp32)
  const int arow4 = lane >> 4;            // row within chunk 0..3
  const int acb   = (lane & 15) * 16;     // byte unit within row
  // B-staging lane constants: 1KB chunks of 8 rows (bf16)
  const int brow8 = lane >> 3;            // 0..7
  const int bcb   = (lane & 7) * 16;      // byte

  f32x4 acc[4][4] = {};

  for (int k0 = 0; k0 < K; k0 += BKs) {
    // stage A fp32: 32 chunks, 8 rounds
#pragma unroll
    for (int i = 0; i < 8; i++) {
      int c = i*4 + w;
      int row = c*4 + arow4;
      int sb = acb ^ ((row & 7) << 4);    // inverse-swizzled source byte
      __builtin_amdgcn_global_load_lds(AS1C(A + (size_t)(m0+row)*K + k0 + (sb >> 2)),
                                       AS3((char*)As + c*1024), 16, 0, 0);
    }
    // stage B bf16: 16 chunks, 4 rounds
#pragma unroll
    for (int i = 0; i < 4; i++) {
      int c = i*4 + w;
      int row = c*8 + brow8;
      int sb = bcb ^ ((row & 7) << 4);
      __builtin_amdgcn_global_load_lds(AS1C((const char*)(Bw + (size_t)(n0+row)*K + k0) + sb),
                                       AS3((char*)Bs + c*1024), 16, 0, 0);
    }
    __syncthreads();
#pragma unroll
    for (int ks = 0; ks < 2; ++ks) {
      bf16x8 af[4], bfr[4];
      const int akb = ks*128 + kgrp*32;   // fp32 byte offset of 8 elems
      const int bkb = ks*64 + kgrp*16;
#pragma unroll
      for (int m = 0; m < 4; m++) {
        int row = wr + m*16 + lrow16;
        int swz = (row & 7) << 4;
        const char* rb = (const char*)As + row*256;
        float4 lo = *(const float4*)(rb + (akb ^ swz));
        float4 hi = *(const float4*)(rb + ((akb + 16) ^ swz));
        bf16x8 a;
        a[0]=(bf16_t)lo.x; a[1]=(bf16_t)lo.y; a[2]=(bf16_t)lo.z; a[3]=(bf16_t)lo.w;
        a[4]=(bf16_t)hi.x; a[5]=(bf16_t)hi.y; a[6]=(bf16_t)hi.z; a[7]=(bf16_t)hi.w;
        af[m] = a;
      }
#pragma unroll
      for (int n = 0; n < 4; n++) {
        int row = wc + n*16 + lrow16;
        bfr[n] = *(const bf16x8*)((const char*)Bs + row*128 + (bkb ^ ((row & 7) << 4)));
      }
#pragma unroll
      for (int m = 0; m < 4; m++)
#pragma unroll
        for (int n = 0; n < 4; n++)
          acc[m][n] = __builtin_amdgcn_mfma_f32_16x16x32_bf16(af[m], bfr[n], acc[m][n], 0, 0, 0);
    }
    __syncthreads();
  }

#pragma unroll
  for (int m = 0; m < 4; m++)
#pragma unroll
    for (int n = 0; n < 4; n++) {
      const int row0 = m0 + wr + m*16 + kgrp*4;
      const int col  = n0 + wc + n*16 + lrow16;
      const float bcol = bias[col];
      if (mode == 2) {
        int b = row0 >> 11, l0 = row0 & 2047;
        int h = col >> 6, dk = col & 63;
        ushort4 u;
        u.x = bfu((acc[m][n][0] + bcol) * scale);
        u.y = bfu((acc[m][n][1] + bcol) * scale);
        u.z = bfu((acc[m][n][2] + bcol) * scale);
        u.w = bfu((acc[m][n][3] + bcol) * scale);
        *(ushort4*)((unsigned short*)out + ((size_t)((b<<4) + h)*DKd + dk)*Ll + l0) = u;
      } else {
#pragma unroll
        for (int i = 0; i < 4; i++) {
          int row = row0 + i;
          float v = (acc[m][n][i] + bcol) * scale;
          if (mode == 1) {
            ((float*)out)[(size_t)row*N + col] = v;
          } else {
            int b = row >> 11, l = row & 2047;
            int h = col >> 6, dk = col & 63;
            ((unsigned short*)out)[((size_t)((b<<4) + h)*Ll + l)*DKd + dk] = bfu(v);
          }
        }
      }
    }
}

// ---------------- O GEMM: BN=64 counted-vmcnt dbuf (round-11 verified) ----------------
#define BM 128
#define BN 64

__device__ __forceinline__ void stage_tile(
    const bf16_t* __restrict__ A, const bf16_t* __restrict__ Bw,
    int m0, int n0, int K, int k0, bf16_t* As, bf16_t* Bs,
    int w, int srow, int scol)
{
#pragma unroll
  for (int i = 0; i < 4; i++) {
    int c = i*4 + w;
    int row = c*8 + srow;
    int sc = scol ^ ((row & 7) << 3);
    __builtin_amdgcn_global_load_lds(AS1C(A + (size_t)(m0+row)*K + k0 + sc),
                                     AS3(As + c*512), 16, 0, 0);
  }
#pragma unroll
  for (int i = 0; i < 2; i++) {
    int c = i*4 + w;
    int row = c*8 + srow;
    int sc = scol ^ ((row & 7) << 3);
    __builtin_amdgcn_global_load_lds(AS1C(Bw + (size_t)(n0+row)*K + k0 + sc),
                                     AS3(Bs + c*512), 16, 0, 0);
  }
}

__global__ __launch_bounds__(256) void gemm_bt(GemmArgs ga, int M, int N, int K)
{
  const int z = blockIdx.z;
  const bf16_t* __restrict__ A  = (const bf16_t*)ga.A[z];
  const bf16_t* __restrict__ Bw = ga.W[z];
  const float*  __restrict__ bias = ga.bias[z];
  void* __restrict__ out = ga.out[z];
  const float scale = ga.scale[z];
  const int mode = ga.mode[z];

  __shared__ bf16_t As[2][BM*BKs];   // 2x16KB
  __shared__ bf16_t Bs[2][BN*BKs];   // 2x8KB
  const int tid = threadIdx.x;
  const int lane = tid & 63;
  const int w = tid >> 6;
  const int m0 = blockIdx.x * BM;
  const int n0 = blockIdx.y * BN;
  const int wr = (w >> 1) * 64, wc = (w & 1) * 32;
  const int lrow16 = lane & 15;
  const int kgrp = lane >> 4;
  const int srow = lane >> 3;
  const int scol = (lane & 7) * 8;

  f32x4 acc[4][2] = {};

  stage_tile(A, Bw, m0, n0, K, 0, As[0], Bs[0], w, srow, scol);

  const int KT = K / BKs;
  int cur = 0;
  for (int kt = 0; kt < KT; ++kt) {
    if (kt + 1 < KT) {
      stage_tile(A, Bw, m0, n0, K, (kt+1)*BKs, As[cur^1], Bs[cur^1], w, srow, scol);
      wait_vm6();
    } else {
      wait_vm0();
    }
    bar();
#pragma unroll
    for (int ks = 0; ks < 2; ++ks) {
      const int kbyte = ks*64 + kgrp*16;
      bf16x8 af[4], bfr[2];
#pragma unroll
      for (int m = 0; m < 4; m++) {
        int row = wr + m*16 + lrow16;
        af[m] = *(const bf16x8*)((const char*)As[cur] + row*128 + (kbyte ^ ((row & 7) << 4)));
      }
#pragma unroll
      for (int n = 0; n < 2; n++) {
        int row = wc + n*16 + lrow16;
        bfr[n] = *(const bf16x8*)((const char*)Bs[cur] + row*128 + (kbyte ^ ((row & 7) << 4)));
      }
#pragma unroll
      for (int m = 0; m < 4; m++)
#pragma unroll
        for (int n = 0; n < 2; n++)
          acc[m][n] = __builtin_amdgcn_mfma_f32_16x16x32_bf16(af[m], bfr[n], acc[m][n], 0, 0, 0);
    }
    bar();
    cur ^= 1;
  }

#pragma unroll
  for (int m = 0; m < 4; m++)
#pragma unroll
    for (int n = 0; n < 2; n++) {
      const int row0 = m0 + wr + m*16 + kgrp*4;
      const int col  = n0 + wc + n*16 + lrow16;
      const float bcol = bias[col];
      if (mode == 2) {
        int b = row0 >> 11, l0 = row0 & 2047;
        int h = col >> 6, dk = col & 63;
        ushort4 u;
        u.x = bfu((acc[m][n][0] + bcol) * scale);
        u.y = bfu((acc[m][n][1] + bcol) * scale);
        u.z = bfu((acc[m][n][2] + bcol) * scale);
        u.w = bfu((acc[m][n][3] + bcol) * scale);
        *(ushort4*)((unsigned short*)out + ((size_t)((b<<4) + h)*DKd + dk)*Ll + l0) = u;
      } else {
#pragma unroll
        for (int i = 0; i < 4; i++) {
          int row = row0 + i;
          float v = (acc[m][n][i] + bcol) * scale;
          if (mode == 1) {
            ((float*)out)[(size_t)row*N + col] = v;
          } else {
            int b = row >> 11, l = row & 2047;
            int h = col >> 6, dk = col & 63;
            ((unsigned short*)out)[((size_t)((b<<4) + h)*Ll + l)*DKd + dk] = bfu(v);
          }
        }
      }
    }
}

// ---------------- causal flash attention (round-11 verified, 48.5us) ----------------
#define KVB 64

__global__ __launch_bounds__(256) void attn_kernel(
    const bf16_t* __restrict__ Qh, const bf16_t* __restrict__ Kh,
    const bf16_t* __restrict__ VTg, unsigned short* __restrict__ Oa)
{
  const int id = blockIdx.x;                 // 0..511
  const int x = id & 7;                      // XCD pin
  const int rest = id >> 3;                  // 0..63
  const int hq = rest >> 4;                  // 0..3
  const int j  = rest & 15;                  // pair index: tiles j and 31-j
  const int bh = x + 8*hq;
  const int sA = j;                          // last step of phase A
  const int qtB = 31 - j;

  const int tid = threadIdx.x, lane = tid & 63, w = tid >> 6;
  const int r = lane & 15, g = lane >> 4;

  const bf16_t* Qp  = Qh  + (size_t)bh * Ll * DKd;
  const bf16_t* Kp  = Kh  + (size_t)bh * Ll * DKd;
  const bf16_t* VTp = VTg + (size_t)bh * Ll * DKd;   // [dk][l]

  __shared__ bf16_t Klds[2][64*64];   // 16KB, XOR-swizzled 128B rows
  __shared__ bf16_t Vlds[2][64*64];   // 16KB, V^T rows (dk), same swizzle
  __shared__ bf16_t Plds[4][16*64];   // 8KB, per-wave P rows (q), swizzled

  int q0 = j * 64;
  bf16x8 qf[2], qB[2];
#pragma unroll
  for (int ks = 0; ks < 2; ++ks) {
    qf[ks] = *(const bf16x8*)(Qp + (size_t)(q0 + w*16 + r)*DKd + ks*32 + g*8);
    qB[ks] = *(const bf16x8*)(Qp + (size_t)(qtB*64 + w*16 + r)*DKd + ks*32 + g*8);
  }

  bf16x8 ones;
#pragma unroll
  for (int jj = 0; jj < 8; ++jj) ones[jj] = (bf16_t)1.0f;

  f32x4 accO[4] = {};
  f32x4 accL = {};
  float mrow = -1e30f;

  const int krow_l = lane >> 3;                        // 0..7
  const int kcol_l = ((lane & 7)*16) ^ (krow_l << 4);  // swizzled source byte
  char* Pw = (char*)&Plds[w][0];
  const int rsw = (r & 7) << 4;
  const int b_ = bh >> 4, h_ = bh & 15;

  auto pre_tiles = [&](int kv, int buf){
#pragma unroll
    for (int i = 0; i < 2; ++i) {
      int c = i*4 + w;
      __builtin_amdgcn_global_load_lds(
        AS1C((const char*)Kp + (size_t)(kv*KVB + c*8 + krow_l)*128 + kcol_l),
        AS3((char*)&Klds[buf][0] + c*1024), 16, 0, 0);
      __builtin_amdgcn_global_load_lds(
        AS1C((const char*)VTp + (size_t)(c*8 + krow_l)*4096 + kv*128 + kcol_l),
        AS3((char*)&Vlds[buf][0] + c*1024), 16, 0, 0);
    }
  };

  pre_tiles(0, 0);   // phase A, kv=0

  int cur = 0;
  for (int s = 0; s < 33; ++s) {
    if (s < 32) {
      int kv2 = (s < sA) ? s + 1 : s - sA;   // next step's kv (phase B restarts at 0)
      pre_tiles(kv2, cur^1);
      wait_vm4();                            // this step's tiles done; next in flight
    } else {
      wait_vm0();
    }
    bar();                                   // staging of [cur] visible to all waves

    const int kv0 = ((s <= sA) ? s : s - sA - 1) * KVB;

    // S^T = K Q^T : sv[n][i] = S[q=q0+w*16+r][kv = kv0 + n*16 + g*4 + i]
    const char* Kbase = (const char*)&Klds[cur][0];
    f32x4 sv[4] = {};
    __builtin_amdgcn_s_setprio(1);
#pragma unroll
    for (int ks = 0; ks < 2; ++ks) {
      const int kbyte = ks*64 + g*16;
#pragma unroll
      for (int n = 0; n < 4; ++n) {
        int row = n*16 + r;
        bf16x8 kf = *(const bf16x8*)(Kbase + row*128 + (kbyte ^ ((row & 7) << 4)));
        sv[n] = __builtin_amdgcn_mfma_f32_16x16x32_bf16(kf, qf[ks], sv[n], 0, 0, 0);
      }
    }
    __builtin_amdgcn_s_setprio(0);

    // causal mask: diagonal tiles only (end of each phase)
    if (s == sA || s == 32) {
      const int qg = q0 + w*16 + r;
#pragma unroll
      for (int n = 0; n < 4; ++n)
#pragma unroll
        for (int i = 0; i < 4; ++i)
          if (kv0 + n*16 + g*4 + i > qg) sv[n][i] = -1e30f;
    }

    // in-register online softmax (log2 domain, defer-max)
    float m0 = fmaxf(fmaxf(sv[0][0], sv[0][1]), sv[0][2]);
    float m1 = fmaxf(fmaxf(sv[0][3], sv[1][0]), sv[1][1]);
    float m2 = fmaxf(fmaxf(sv[1][2], sv[1][3]), sv[2][0]);
    float m3 = fmaxf(fmaxf(sv[2][1], sv[2][2]), sv[2][3]);
    float m4 = fmaxf(fmaxf(sv[3][0], sv[3][1]), sv[3][2]);
    float mx = fmaxf(fmaxf(fmaxf(m0, m1), m2), fmaxf(fmaxf(m3, m4), sv[3][3]));
    if (__any(mx > mrow + 8.f)) {
      mx = fmaxf(mx, __shfl_xor(mx, 16));
      mx = fmaxf(mx, __shfl_xor(mx, 32));
      float mnew = fmaxf(mrow, mx);
      float corr = __builtin_amdgcn_exp2f(mrow - mnew);
      float c0 = __shfl(corr, g*4 + 0);
      float c1 = __shfl(corr, g*4 + 1);
      float c2 = __shfl(corr, g*4 + 2);
      float c3 = __shfl(corr, g*4 + 3);
#pragma unroll
      for (int n = 0; n < 4; ++n) {
        accO[n][0] *= c0; accO[n][1] *= c1; accO[n][2] *= c2; accO[n][3] *= c3;
      }
      accL[0] *= c0; accL[1] *= c1; accL[2] *= c2; accL[3] *= c3;
      mrow = mnew;
    }
#pragma unroll
    for (int n = 0; n < 4; ++n)
#pragma unroll
      for (int i = 0; i < 4; ++i)
        sv[n][i] = __builtin_amdgcn_exp2f(sv[n][i] - mrow);

    // pack P -> per-wave LDS: 4 x b64 swizzled writes (same-wave, no barrier)
#pragma unroll
    for (int n = 0; n < 4; ++n) {
      unsigned lo = (unsigned)bfu(sv[n][0]) | ((unsigned)bfu(sv[n][1]) << 16);
      unsigned hi = (unsigned)bfu(sv[n][2]) | ((unsigned)bfu(sv[n][3]) << 16);
      u32x2 pk; pk[0] = lo; pk[1] = hi;
      *(u32x2*)(Pw + r*128 + ((n*32 + g*8) ^ rsw)) = pk;
    }

    // PV: O += P * V, l += P * 1
    const char* Vbase = (const char*)&Vlds[cur][0];
    __builtin_amdgcn_s_setprio(1);
#pragma unroll
    for (int ks = 0; ks < 2; ++ks) {
      const int kbyte = ks*64 + g*16;
      bf16x8 pa = *(const bf16x8*)(Pw + r*128 + (kbyte ^ rsw));
      accL = __builtin_amdgcn_mfma_f32_16x16x32_bf16(pa, ones, accL, 0, 0, 0);
#pragma unroll
      for (int n = 0; n < 4; ++n) {
        int row = n*16 + r;
        bf16x8 vf = *(const bf16x8*)(Vbase + row*128 + (kbyte ^ ((row & 7) << 4)));
        accO[n] = __builtin_amdgcn_mfma_f32_16x16x32_bf16(pa, vf, accO[n], 0, 0, 0);
      }
    }
    __builtin_amdgcn_s_setprio(0);

    // phase A finished: store, reset, switch to tile B's Q
    if (s == sA) {
#pragma unroll
      for (int i = 0; i < 4; ++i) {
        float inv = 1.f / accL[i];
        int q = q0 + w*16 + g*4 + i;
#pragma unroll
        for (int n = 0; n < 4; ++n)
          Oa[((size_t)(b_*Ll + q))*Dd + h_*DKd + n*16 + r] = bfu(accO[n][i] * inv);
      }
      q0 = qtB * 64;
      qf[0] = qB[0]; qf[1] = qB[1];
#pragma unroll
      for (int n = 0; n < 4; ++n) accO[n] = f32x4{};
      accL = f32x4{};
      mrow = -1e30f;
    }

    bar();                                   // all reads of [cur] done before reuse
    cur ^= 1;
  }

  // phase B store
#pragma unroll
  for (int i = 0; i < 4; ++i) {
    float inv = 1.f / accL[i];
    int q = q0 + w*16 + g*4 + i;
#pragma unroll
    for (int n = 0; n < 4; ++n)
      Oa[((size_t)(b_*Ll + q))*Dd + h_*DKd + n*16 + r] = bfu(accO[n][i] * inv);
  }
}

// ---------------- launch ----------------
extern "C" void kernel_launch(void* const* d_in, const int* in_sizes, int n_in,
                              void* d_out, int out_size, void* d_ws, size_t ws_size,
                              hipStream_t stream)
{
  const float* q  = (const float*)d_in[0];
  const float* k  = (const float*)d_in[1];
  const float* v  = (const float*)d_in[2];
  // d_in[3] = mask (causal, hardcoded)
  const float* wq = (const float*)d_in[4];
  const float* bq = (const float*)d_in[5];
  const float* wk = (const float*)d_in[6];
  const float* bk = (const float*)d_in[7];
  const float* wv = (const float*)d_in[8];
  const float* bv = (const float*)d_in[9];
  const float* wo = (const float*)d_in[10];
  const float* bo = (const float*)d_in[11];

  char* ws = (char*)d_ws;
  bf16_t* Wq = (bf16_t*)(ws + 25165824);
  bf16_t* Wk = (bf16_t*)(ws + 27262976);
  bf16_t* Wv = (bf16_t*)(ws + 29360128);
  bf16_t* Wo = (bf16_t*)(ws + 31457280);
  bf16_t* Qh = (bf16_t*)(ws + 33554432);
  bf16_t* Kh = (bf16_t*)(ws + 41943040);
  bf16_t* VT = (bf16_t*)(ws + 50331648);   // V^T (B,H,DK,L), written by V-GEMM
  bf16_t* Oa = (bf16_t*)(ws + 58720256);   // total 64 MiB

  const int NW4 = Dd * Dd / 4;   // 262144

  Cvt4 cv;
  cv.in[0]=wq; cv.out[0]=(ushort4*)Wq;
  cv.in[1]=wk; cv.out[1]=(ushort4*)Wk;
  cv.in[2]=wv; cv.out[2]=(ushort4*)Wv;
  cv.in[3]=wo; cv.out[3]=(ushort4*)Wo;
  cvt_multi<<<dim3(NW4/256, 4), 256, 0, stream>>>(cv, NW4);

  const float qscale = 0.125f * 1.4426950408889634f;  // 1/sqrt(DK) * log2(e)
  GemmArgs gqkv;
  gqkv.A[0]=q; gqkv.A[1]=k; gqkv.A[2]=v;              // fp32 inputs, in-GEMM convert
  gqkv.W[0]=Wq; gqkv.W[1]=Wk; gqkv.W[2]=Wv;
  gqkv.bias[0]=bq; gqkv.bias[1]=bk; gqkv.bias[2]=bv;
  gqkv.out[0]=Qh; gqkv.out[1]=Kh; gqkv.out[2]=VT;
  gqkv.scale[0]=qscale; gqkv.scale[1]=1.0f; gqkv.scale[2]=1.0f;
  gqkv.mode[0]=0; gqkv.mode[1]=0; gqkv.mode[2]=2;     // V writes V^T directly
  gemm128_f32<<<dim3(Mm/128, Dd/128, 3), 256, 0, stream>>>(gqkv, Mm, Dd, Dd);

  attn_kernel<<<dim3(512), 256, 0, stream>>>(Qh, Kh, VT, (unsigned short*)Oa);

  GemmArgs go;
  go.A[0]=Oa; go.A[1]=Oa; go.A[2]=Oa;
  go.W[0]=Wo; go.W[1]=Wo; go.W[2]=Wo;
  go.bias[0]=bo; go.bias[1]=bo; go.bias[2]=bo;
  go.out[0]=d_out; go.out[1]=d_out; go.out[2]=d_out;
  go.scale[0]=1.0f; go.scale[1]=1.0f; go.scale[2]=1.0f;
  go.mode[0]=1; go.mode[1]=1; go.mode[2]=1;
  gemm_bt<<<dim3(Mm/BM, Dd/BN, 1), 256, 0, stream>>>(go, Mm, Dd, Dd);
}

// Round 14
// 107.801 us; speedup vs baseline: 1.3200x; 1.0163x over previous
//
#include <hip/hip_runtime.h>
#include <stdint.h>

#define Bb 2
#define Ll 2048
#define Dd 1024
#define Hh 16
#define DKd 64
#define Mm (Bb*Ll)   // 4096

typedef __bf16 bf16_t;
typedef __bf16 bf16x8 __attribute__((ext_vector_type(8)));
typedef float f32x4 __attribute__((ext_vector_type(4)));
typedef unsigned u32x2 __attribute__((ext_vector_type(2)));

#define AS1C(p) ((const __attribute__((address_space(1))) void*)(p))
#define AS3(p)  ((__attribute__((address_space(3))) void*)(p))

__device__ __forceinline__ unsigned short bfu(float f){
  return __builtin_bit_cast(unsigned short, (bf16_t)f);   // native v_cvt, RTNE
}
__device__ __forceinline__ void wait_vm4(){ asm volatile("s_waitcnt vmcnt(4)" ::: "memory"); }
__device__ __forceinline__ void wait_vm6(){ asm volatile("s_waitcnt vmcnt(6)" ::: "memory"); }
__device__ __forceinline__ void wait_vm0(){ asm volatile("s_waitcnt vmcnt(0)" ::: "memory"); }
__device__ __forceinline__ void wait_lgkm0(){ asm volatile("s_waitcnt lgkmcnt(0)" ::: "memory"); }
__device__ __forceinline__ void bar(){
  __builtin_amdgcn_sched_barrier(0);
  __builtin_amdgcn_s_barrier();
  __builtin_amdgcn_sched_barrier(0);
}

// ---------------- fp32 -> bf16 convert: weights only ----------------
struct Cvt4 { const float* in[4]; ushort4* out[4]; };

__global__ void cvt_multi(Cvt4 a, int n4){
  const int z = blockIdx.y;
  int i = blockIdx.x*256 + threadIdx.x;
  if (i < n4){
    float4 v = ((const float4*)a.in[z])[i];
    ushort4 o; o.x=bfu(v.x); o.y=bfu(v.y); o.z=bfu(v.z); o.w=bfu(v.w);
    a.out[z][i] = o;
  }
}

// ---------------- shared GEMM pieces ----------------
struct GemmArgs {
  const void*   A[3];    // fp32 for gemm128_ra, bf16 for gemm_bt
  const bf16_t* W[3];
  const float*  bias[3];
  void*         out[3];
  float         scale[3];
  int           mode[3];   // 0: bf16 (B,H,L,DK); 1: fp32 row-major; 2: bf16 V^T (B,H,DK,L)
};

#define BKs 64

// ---------------- QKV GEMM: 128x128, fp32 A reg-staged -> bf16 LDS ----------------
// A: global fp32 -> regs (prefetched across compute) -> cvt -> ds_write bf16.
// B: bf16 via swizzled global_load_lds, double-buffered, counted vmcnt.
__global__ __launch_bounds__(256) void gemm128_ra(GemmArgs ga, int M, int N, int K)
{
  const int z = blockIdx.z;
  const float*  __restrict__ A  = (const float*)ga.A[z];
  const bf16_t* __restrict__ Bw = ga.W[z];
  const float*  __restrict__ bias = ga.bias[z];
  void* __restrict__ out = ga.out[z];
  const float scale = ga.scale[z];
  const int mode = ga.mode[z];

  __shared__ bf16_t As[128*BKs];      // 16KB single (reg prefetch covers latency)
  __shared__ bf16_t Bs[2][128*BKs];   // 2x16KB dbuf
  const int tid = threadIdx.x;
  const int lane = tid & 63;
  const int w = tid >> 6;
  const int m0 = blockIdx.x * 128;
  const int n0 = blockIdx.y * 128;
  const int wr = (w >> 1) * 64, wc = (w & 1) * 64;
  const int lrow16 = lane & 15;
  const int kgrp = lane >> 4;

  // B staging lane constants (verified r12/r13 path)
  const int brow8 = lane >> 3;
  const int bcb   = (lane & 7) * 16;
  // A reg-staging constants: round i covers rows i*32 + (tid>>3), cols (tid&7)*8 fp32
  const int arow  = tid >> 3;                              // 0..31
  const int awb   = ((tid & 7) * 16) ^ ((arow & 7) << 4);  // swizzled write byte (row&7 == arow&7)

  f32x4 ar[4][2];

  auto loadA = [&](int k0){
#pragma unroll
    for (int i = 0; i < 4; ++i) {
      const float* p = A + (size_t)(m0 + i*32 + arow)*K + k0 + (tid & 7)*8;
      ar[i][0] = *(const f32x4*)p;
      ar[i][1] = *(const f32x4*)(p + 4);
    }
  };
  auto writeA = [&](){
#pragma unroll
    for (int i = 0; i < 4; ++i) {
      bf16x8 a;
      a[0]=(bf16_t)ar[i][0][0]; a[1]=(bf16_t)ar[i][0][1];
      a[2]=(bf16_t)ar[i][0][2]; a[3]=(bf16_t)ar[i][0][3];
      a[4]=(bf16_t)ar[i][1][0]; a[5]=(bf16_t)ar[i][1][1];
      a[6]=(bf16_t)ar[i][1][2]; a[7]=(bf16_t)ar[i][1][3];
      *(bf16x8*)((char*)As + (i*32 + arow)*128 + awb) = a;
    }
  };
  auto stageB = [&](int k0, int buf){
#pragma unroll
    for (int i = 0; i < 4; ++i) {
      int c = i*4 + w;
      int row = c*8 + brow8;
      int sb = bcb ^ ((row & 7) << 4);
      __builtin_amdgcn_global_load_lds(AS1C((const char*)(Bw + (size_t)(n0+row)*K + k0) + sb),
                                       AS3((char*)&Bs[buf][0] + c*1024), 16, 0, 0);
    }
  };

  f32x4 acc[4][4] = {};

  loadA(0);
  stageB(0, 0);
  wait_vm0();          // B(0) in LDS; A(0) regs ready (compiler also tracks reg deps)
  writeA();
  wait_lgkm0();
  bar();

  const int KT = K / BKs;
  int cur = 0;
  for (int kt = 0; kt < KT; ++kt) {
    const bool pre = (kt + 1 < KT);
    if (pre) {
      loadA((kt+1)*BKs);          // 8 VMEM events (older)
      stageB((kt+1)*BKs, cur^1);  // 4 VMEM events (newer)
    }
#pragma unroll
    for (int ks = 0; ks < 2; ++ks) {
      const int kbyte = ks*64 + kgrp*16;
      bf16x8 af[4], bfr[4];
#pragma unroll
      for (int m = 0; m < 4; m++) {
        int row = wr + m*16 + lrow16;
        af[m] = *(const bf16x8*)((const char*)As + row*128 + (kbyte ^ ((row & 7) << 4)));
      }
#pragma unroll
      for (int n = 0; n < 4; n++) {
        int row = wc + n*16 + lrow16;
        bfr[n] = *(const bf16x8*)((const char*)&Bs[cur][0] + row*128 + (kbyte ^ ((row & 7) << 4)));
      }
#pragma unroll
      for (int m = 0; m < 4; m++)
#pragma unroll
        for (int n = 0; n < 4; n++)
          acc[m][n] = __builtin_amdgcn_mfma_f32_16x16x32_bf16(af[m], bfr[n], acc[m][n], 0, 0, 0);
    }
    if (pre) wait_vm4();          // A(kt+1) regs arrived; B(kt+1) may stay in flight
    bar();                        // all waves done reading As(kt) / Bs[cur]
    if (pre) {
      writeA();                   // As <- tile kt+1 (bf16)
      wait_vm0();                 // B(kt+1) landed (issued a full compute-phase ago)
      wait_lgkm0();               // own ds_writes drained
    }
    bar();                        // As(kt+1)/Bs[cur^1] visible to all waves
    cur ^= 1;
  }

#pragma unroll
  for (int m = 0; m < 4; m++)
#pragma unroll
    for (int n = 0; n < 4; n++) {
      const int row0 = m0 + wr + m*16 + kgrp*4;
      const int col  = n0 + wc + n*16 + lrow16;
      const float bcol = bias[col];
      if (mode == 2) {
        int b = row0 >> 11, l0 = row0 & 2047;
        int h = col >> 6, dk = col & 63;
        ushort4 u;
        u.x = bfu((acc[m][n][0] + bcol) * scale);
        u.y = bfu((acc[m][n][1] + bcol) * scale);
        u.z = bfu((acc[m][n][2] + bcol) * scale);
        u.w = bfu((acc[m][n][3] + bcol) * scale);
        *(ushort4*)((unsigned short*)out + ((size_t)((b<<4) + h)*DKd + dk)*Ll + l0) = u;
      } else {
#pragma unroll
        for (int i = 0; i < 4; i++) {
          int row = row0 + i;
          float v = (acc[m][n][i] + bcol) * scale;
          if (mode == 1) {
            ((float*)out)[(size_t)row*N + col] = v;
          } else {
            int b = row >> 11, l = row & 2047;
            int h = col >> 6, dk = col & 63;
            ((unsigned short*)out)[((size_t)((b<<4) + h)*Ll + l)*DKd + dk] = bfu(v);
          }
        }
      }
    }
}

// ---------------- O GEMM: BN=64 counted-vmcnt dbuf (round-11 verified) ----------------
#define BM 128
#define BN 64

__device__ __forceinline__ void stage_tile(
    const bf16_t* __restrict__ A, const bf16_t* __restrict__ Bw,
    int m0, int n0, int K, int k0, bf16_t* As, bf16_t* Bs,
    int w, int srow, int scol)
{
#pragma unroll
  for (int i = 0; i < 4; i++) {
    int c = i*4 + w;
    int row = c*8 + srow;
    int sc = scol ^ ((row & 7) << 3);
    __builtin_amdgcn_global_load_lds(AS1C(A + (size_t)(m0+row)*K + k0 + sc),
                                     AS3(As + c*512), 16, 0, 0);
  }
#pragma unroll
  for (int i = 0; i < 2; i++) {
    int c = i*4 + w;
    int row = c*8 + srow;
    int sc = scol ^ ((row & 7) << 3);
    __builtin_amdgcn_global_load_lds(AS1C(Bw + (size_t)(n0+row)*K + k0 + sc),
                                     AS3(Bs + c*512), 16, 0, 0);
  }
}

__global__ __launch_bounds__(256) void gemm_bt(GemmArgs ga, int M, int N, int K)
{
  const int z = blockIdx.z;
  const bf16_t* __restrict__ A  = (const bf16_t*)ga.A[z];
  const bf16_t* __restrict__ Bw = ga.W[z];
  const float*  __restrict__ bias = ga.bias[z];
  void* __restrict__ out = ga.out[z];
  const float scale = ga.scale[z];
  const int mode = ga.mode[z];

  __shared__ bf16_t As[2][BM*BKs];   // 2x16KB
  __shared__ bf16_t Bs[2][BN*BKs];   // 2x8KB
  const int tid = threadIdx.x;
  const int lane = tid & 63;
  const int w = tid >> 6;
  const int m0 = blockIdx.x * BM;
  const int n0 = blockIdx.y * BN;
  const int wr = (w >> 1) * 64, wc = (w & 1) * 32;
  const int lrow16 = lane & 15;
  const int kgrp = lane >> 4;
  const int srow = lane >> 3;
  const int scol = (lane & 7) * 8;

  f32x4 acc[4][2] = {};

  stage_tile(A, Bw, m0, n0, K, 0, As[0], Bs[0], w, srow, scol);

  const int KT = K / BKs;
  int cur = 0;
  for (int kt = 0; kt < KT; ++kt) {
    if (kt + 1 < KT) {
      stage_tile(A, Bw, m0, n0, K, (kt+1)*BKs, As[cur^1], Bs[cur^1], w, srow, scol);
      wait_vm6();
    } else {
      wait_vm0();
    }
    bar();
#pragma unroll
    for (int ks = 0; ks < 2; ++ks) {
      const int kbyte = ks*64 + kgrp*16;
      bf16x8 af[4], bfr[2];
#pragma unroll
      for (int m = 0; m < 4; m++) {
        int row = wr + m*16 + lrow16;
        af[m] = *(const bf16x8*)((const char*)As[cur] + row*128 + (kbyte ^ ((row & 7) << 4)));
      }
#pragma unroll
      for (int n = 0; n < 2; n++) {
        int row = wc + n*16 + lrow16;
        bfr[n] = *(const bf16x8*)((const char*)Bs[cur] + row*128 + (kbyte ^ ((row & 7) << 4)));
      }
#pragma unroll
      for (int m = 0; m < 4; m++)
#pragma unroll
        for (int n = 0; n < 2; n++)
          acc[m][n] = __builtin_amdgcn_mfma_f32_16x16x32_bf16(af[m], bfr[n], acc[m][n], 0, 0, 0);
    }
    bar();
    cur ^= 1;
  }

#pragma unroll
  for (int m = 0; m < 4; m++)
#pragma unroll
    for (int n = 0; n < 2; n++) {
      const int row0 = m0 + wr + m*16 + kgrp*4;
      const int col  = n0 + wc + n*16 + lrow16;
      const float bcol = bias[col];
      if (mode == 2) {
        int b = row0 >> 11, l0 = row0 & 2047;
        int h = col >> 6, dk = col & 63;
        ushort4 u;
        u.x = bfu((acc[m][n][0] + bcol) * scale);
        u.y = bfu((acc[m][n][1] + bcol) * scale);
        u.z = bfu((acc[m][n][2] + bcol) * scale);
        u.w = bfu((acc[m][n][3] + bcol) * scale);
        *(ushort4*)((unsigned short*)out + ((size_t)((b<<4) + h)*DKd + dk)*Ll + l0) = u;
      } else {
#pragma unroll
        for (int i = 0; i < 4; i++) {
          int row = row0 + i;
          float v = (acc[m][n][i] + bcol) * scale;
          if (mode == 1) {
            ((float*)out)[(size_t)row*N + col] = v;
          } else {
            int b = row >> 11, l = row & 2047;
            int h = col >> 6, dk = col & 63;
            ((unsigned short*)out)[((size_t)((b<<4) + h)*Ll + l)*DKd + dk] = bfu(v);
          }
        }
      }
    }
}

// ---------------- causal flash attention (round-11 verified, 48.5us) ----------------
#define KVB 64

__global__ __launch_bounds__(256) void attn_kernel(
    const bf16_t* __restrict__ Qh, const bf16_t* __restrict__ Kh,
    const bf16_t* __restrict__ VTg, unsigned short* __restrict__ Oa)
{
  const int id = blockIdx.x;                 // 0..511
  const int x = id & 7;                      // XCD pin
  const int rest = id >> 3;                  // 0..63
  const int hq = rest >> 4;                  // 0..3
  const int j  = rest & 15;                  // pair index: tiles j and 31-j
  const int bh = x + 8*hq;
  const int sA = j;                          // last step of phase A
  const int qtB = 31 - j;

  const int tid = threadIdx.x, lane = tid & 63, w = tid >> 6;
  const int r = lane & 15, g = lane >> 4;

  const bf16_t* Qp  = Qh  + (size_t)bh * Ll * DKd;
  const bf16_t* Kp  = Kh  + (size_t)bh * Ll * DKd;
  const bf16_t* VTp = VTg + (size_t)bh * Ll * DKd;   // [dk][l]

  __shared__ bf16_t Klds[2][64*64];   // 16KB, XOR-swizzled 128B rows
  __shared__ bf16_t Vlds[2][64*64];   // 16KB, V^T rows (dk), same swizzle
  __shared__ bf16_t Plds[4][16*64];   // 8KB, per-wave P rows (q), swizzled

  int q0 = j * 64;
  bf16x8 qf[2], qB[2];
#pragma unroll
  for (int ks = 0; ks < 2; ++ks) {
    qf[ks] = *(const bf16x8*)(Qp + (size_t)(q0 + w*16 + r)*DKd + ks*32 + g*8);
    qB[ks] = *(const bf16x8*)(Qp + (size_t)(qtB*64 + w*16 + r)*DKd + ks*32 + g*8);
  }

  bf16x8 ones;
#pragma unroll
  for (int jj = 0; jj < 8; ++jj) ones[jj] = (bf16_t)1.0f;

  f32x4 accO[4] = {};
  f32x4 accL = {};
  float mrow = -1e30f;

  const int krow_l = lane >> 3;                        // 0..7
  const int kcol_l = ((lane & 7)*16) ^ (krow_l << 4);  // swizzled source byte
  char* Pw = (char*)&Plds[w][0];
  const int rsw = (r & 7) << 4;
  const int b_ = bh >> 4, h_ = bh & 15;

  auto pre_tiles = [&](int kv, int buf){
#pragma unroll
    for (int i = 0; i < 2; ++i) {
      int c = i*4 + w;
      __builtin_amdgcn_global_load_lds(
        AS1C((const char*)Kp + (size_t)(kv*KVB + c*8 + krow_l)*128 + kcol_l),
        AS3((char*)&Klds[buf][0] + c*1024), 16, 0, 0);
      __builtin_amdgcn_global_load_lds(
        AS1C((const char*)VTp + (size_t)(c*8 + krow_l)*4096 + kv*128 + kcol_l),
        AS3((char*)&Vlds[buf][0] + c*1024), 16, 0, 0);
    }
  };

  pre_tiles(0, 0);   // phase A, kv=0

  int cur = 0;
  for (int s = 0; s < 33; ++s) {
    if (s < 32) {
      int kv2 = (s < sA) ? s + 1 : s - sA;   // next step's kv (phase B restarts at 0)
      pre_tiles(kv2, cur^1);
      wait_vm4();                            // this step's tiles done; next in flight
    } else {
      wait_vm0();
    }
    bar();                                   // staging of [cur] visible to all waves

    const int kv0 = ((s <= sA) ? s : s - sA - 1) * KVB;

    // S^T = K Q^T : sv[n][i] = S[q=q0+w*16+r][kv = kv0 + n*16 + g*4 + i]
    const char* Kbase = (const char*)&Klds[cur][0];
    f32x4 sv[4] = {};
    __builtin_amdgcn_s_setprio(1);
#pragma unroll
    for (int ks = 0; ks < 2; ++ks) {
      const int kbyte = ks*64 + g*16;
#pragma unroll
      for (int n = 0; n < 4; ++n) {
        int row = n*16 + r;
        bf16x8 kf = *(const bf16x8*)(Kbase + row*128 + (kbyte ^ ((row & 7) << 4)));
        sv[n] = __builtin_amdgcn_mfma_f32_16x16x32_bf16(kf, qf[ks], sv[n], 0, 0, 0);
      }
    }
    __builtin_amdgcn_s_setprio(0);

    // causal mask: diagonal tiles only (end of each phase)
    if (s == sA || s == 32) {
      const int qg = q0 + w*16 + r;
#pragma unroll
      for (int n = 0; n < 4; ++n)
#pragma unroll
        for (int i = 0; i < 4; ++i)
          if (kv0 + n*16 + g*4 + i > qg) sv[n][i] = -1e30f;
    }

    // in-register online softmax (log2 domain, defer-max)
    float m0 = fmaxf(fmaxf(sv[0][0], sv[0][1]), sv[0][2]);
    float m1 = fmaxf(fmaxf(sv[0][3], sv[1][0]), sv[1][1]);
    float m2 = fmaxf(fmaxf(sv[1][2], sv[1][3]), sv[2][0]);
    float m3 = fmaxf(fmaxf(sv[2][1], sv[2][2]), sv[2][3]);
    float m4 = fmaxf(fmaxf(sv[3][0], sv[3][1]), sv[3][2]);
    float mx = fmaxf(fmaxf(fmaxf(m0, m1), m2), fmaxf(fmaxf(m3, m4), sv[3][3]));
    if (__any(mx > mrow + 8.f)) {
      mx = fmaxf(mx, __shfl_xor(mx, 16));
      mx = fmaxf(mx, __shfl_xor(mx, 32));
      float mnew = fmaxf(mrow, mx);
      float corr = __builtin_amdgcn_exp2f(mrow - mnew);
      float c0 = __shfl(corr, g*4 + 0);
      float c1 = __shfl(corr, g*4 + 1);
      float c2 = __shfl(corr, g*4 + 2);
      float c3 = __shfl(corr, g*4 + 3);
#pragma unroll
      for (int n = 0; n < 4; ++n) {
        accO[n][0] *= c0; accO[n][1] *= c1; accO[n][2] *= c2; accO[n][3] *= c3;
      }
      accL[0] *= c0; accL[1] *= c1; accL[2] *= c2; accL[3] *= c3;
      mrow = mnew;
    }
#pragma unroll
    for (int n = 0; n < 4; ++n)
#pragma unroll
      for (int i = 0; i < 4; ++i)
        sv[n][i] = __builtin_amdgcn_exp2f(sv[n][i] - mrow);

    // pack P -> per-wave LDS: 4 x b64 swizzled writes (same-wave, no barrier)
#pragma unroll
    for (int n = 0; n < 4; ++n) {
      unsigned lo = (unsigned)bfu(sv[n][0]) | ((unsigned)bfu(sv[n][1]) << 16);
      unsigned hi = (unsigned)bfu(sv[n][2]) | ((unsigned)bfu(sv[n][3]) << 16);
      u32x2 pk; pk[0] = lo; pk[1] = hi;
      *(u32x2*)(Pw + r*128 + ((n*32 + g*8) ^ rsw)) = pk;
    }

    // PV: O += P * V, l += P * 1
    const char* Vbase = (const char*)&Vlds[cur][0];
    __builtin_amdgcn_s_setprio(1);
#pragma unroll
    for (int ks = 0; ks < 2; ++ks) {
      const int kbyte = ks*64 + g*16;
      bf16x8 pa = *(const bf16x8*)(Pw + r*128 + (kbyte ^ rsw));
      accL = __builtin_amdgcn_mfma_f32_16x16x32_bf16(pa, ones, accL, 0, 0, 0);
#pragma unroll
      for (int n = 0; n < 4; ++n) {
        int row = n*16 + r;
        bf16x8 vf = *(const bf16x8*)(Vbase + row*128 + (kbyte ^ ((row & 7) << 4)));
        accO[n] = __builtin_amdgcn_mfma_f32_16x16x32_bf16(pa, vf, accO[n], 0, 0, 0);
      }
    }
    __builtin_amdgcn_s_setprio(0);

    // phase A finished: store, reset, switch to tile B's Q
    if (s == sA) {
#pragma unroll
      for (int i = 0; i < 4; ++i) {
        float inv = 1.f / accL[i];
        int q = q0 + w*16 + g*4 + i;
#pragma unroll
        for (int n = 0; n < 4; ++n)
          Oa[((size_t)(b_*Ll + q))*Dd + h_*DKd + n*16 + r] = bfu(accO[n][i] * inv);
      }
      q0 = qtB * 64;
      qf[0] = qB[0]; qf[1] = qB[1];
#pragma unroll
      for (int n = 0; n < 4; ++n) accO[n] = f32x4{};
      accL = f32x4{};
      mrow = -1e30f;
    }

    bar();                                   // all reads of [cur] done before reuse
    cur ^= 1;
  }

  // phase B store
#pragma unroll
  for (int i = 0; i < 4; ++i) {
    float inv = 1.f / accL[i];
    int q = q0 + w*16 + g*4 + i;
#pragma unroll
    for (int n = 0; n < 4; ++n)
      Oa[((size_t)(b_*Ll + q))*Dd + h_*DKd + n*16 + r] = bfu(accO[n][i] * inv);
  }
}

// ---------------- launch ----------------
extern "C" void kernel_launch(void* const* d_in, const int* in_sizes, int n_in,
                              void* d_out, int out_size, void* d_ws, size_t ws_size,
                              hipStream_t stream)
{
  const float* q  = (const float*)d_in[0];
  const float* k  = (const float*)d_in[1];
  const float* v  = (const float*)d_in[2];
  // d_in[3] = mask (causal, hardcoded)
  const float* wq = (const float*)d_in[4];
  const float* bq = (const float*)d_in[5];
  const float* wk = (const float*)d_in[6];
  const float* bk = (const float*)d_in[7];
  const float* wv = (const float*)d_in[8];
  const float* bv = (const float*)d_in[9];
  const float* wo = (const float*)d_in[10];
  const float* bo = (const float*)d_in[11];

  char* ws = (char*)d_ws;
  bf16_t* Wq = (bf16_t*)(ws + 25165824);
  bf16_t* Wk = (bf16_t*)(ws + 27262976);
  bf16_t* Wv = (bf16_t*)(ws + 29360128);
  bf16_t* Wo = (bf16_t*)(ws + 31457280);
  bf16_t* Qh = (bf16_t*)(ws + 33554432);
  bf16_t* Kh = (bf16_t*)(ws + 41943040);
  bf16_t* VT = (bf16_t*)(ws + 50331648);   // V^T (B,H,DK,L), written by V-GEMM
  bf16_t* Oa = (bf16_t*)(ws + 58720256);   // total 64 MiB

  const int NW4 = Dd * Dd / 4;   // 262144

  Cvt4 cv;
  cv.in[0]=wq; cv.out[0]=(ushort4*)Wq;
  cv.in[1]=wk; cv.out[1]=(ushort4*)Wk;
  cv.in[2]=wv; cv.out[2]=(ushort4*)Wv;
  cv.in[3]=wo; cv.out[3]=(ushort4*)Wo;
  cvt_multi<<<dim3(NW4/256, 4), 256, 0, stream>>>(cv, NW4);

  const float qscale = 0.125f * 1.4426950408889634f;  // 1/sqrt(DK) * log2(e)
  GemmArgs gqkv;
  gqkv.A[0]=q; gqkv.A[1]=k; gqkv.A[2]=v;              // fp32 inputs, in-GEMM convert
  gqkv.W[0]=Wq; gqkv.W[1]=Wk; gqkv.W[2]=Wv;
  gqkv.bias[0]=bq; gqkv.bias[1]=bk; gqkv.bias[2]=bv;
  gqkv.out[0]=Qh; gqkv.out[1]=Kh; gqkv.out[2]=VT;
  gqkv.scale[0]=qscale; gqkv.scale[1]=1.0f; gqkv.scale[2]=1.0f;
  gqkv.mode[0]=0; gqkv.mode[1]=0; gqkv.mode[2]=2;     // V writes V^T directly
  gemm128_ra<<<dim3(Mm/128, Dd/128, 3), 256, 0, stream>>>(gqkv, Mm, Dd, Dd);

  attn_kernel<<<dim3(512), 256, 0, stream>>>(Qh, Kh, VT, (unsigned short*)Oa);

  GemmArgs go;
  go.A[0]=Oa; go.A[1]=Oa; go.A[2]=Oa;
  go.W[0]=Wo; go.W[1]=Wo; go.W[2]=Wo;
  go.bias[0]=bo; go.bias[1]=bo; go.bias[2]=bo;
  go.out[0]=d_out; go.out[1]=d_out; go.out[2]=d_out;
  go.scale[0]=1.0f; go.scale[1]=1.0f; go.scale[2]=1.0f;
  go.mode[0]=1; go.mode[1]=1; go.mode[2]=1;
  gemm_bt<<<dim3(Mm/BM, Dd/BN, 1), 256, 0, stream>>>(go, Mm, Dd, Dd);
}